// Round 1
// baseline (2181.955 us; speedup 1.0000x reference)
//
#include <hip/hip_runtime.h>

#define N_NODES 100000
#define N_EDGES 3200000
#define DIM 128
#define N_LAYERS 3
#define NUM_GRAPHS 128
#define BN_EPS 1e-5f

#define SCAN_CHUNK 1024
#define NBLK_SCAN ((N_NODES + SCAN_CHUNK - 1) / SCAN_CHUNK)  // 98

// ---------------------------------------------------------------------------
// CSR build: histogram -> scan -> scatter
// ---------------------------------------------------------------------------
__global__ __launch_bounds__(256) void hist_kernel(const int* __restrict__ dst,
                                                   int* __restrict__ deg) {
    int e = blockIdx.x * 256 + threadIdx.x;
    if (e < N_EDGES) atomicAdd(&deg[dst[e]], 1);
}

__global__ __launch_bounds__(256) void scan_partial(const int* __restrict__ deg,
                                                    int* __restrict__ bsum) {
    int b = blockIdx.x, t = threadIdx.x;
    int base = b * SCAN_CHUNK + t * 4;
    int s = 0;
#pragma unroll
    for (int j = 0; j < 4; ++j) {
        int idx = base + j;
        if (idx < N_NODES) s += deg[idx];
    }
#pragma unroll
    for (int off = 32; off >= 1; off >>= 1) s += __shfl_down(s, off);
    __shared__ int wsum[4];
    int lane = t & 63, wid = t >> 6;
    if (lane == 0) wsum[wid] = s;
    __syncthreads();
    if (t == 0) bsum[b] = wsum[0] + wsum[1] + wsum[2] + wsum[3];
}

__global__ void scan_mid(int* __restrict__ bsum, int* __restrict__ row_ptr) {
    if (threadIdx.x == 0 && blockIdx.x == 0) {
        int excl = 0;
        for (int b = 0; b < NBLK_SCAN; ++b) {
            int v = bsum[b];
            bsum[b] = excl;
            excl += v;
        }
        row_ptr[N_NODES] = excl;  // == N_EDGES
    }
}

__global__ __launch_bounds__(256) void scan_final(const int* __restrict__ deg,
                                                  const int* __restrict__ bsum,
                                                  int* __restrict__ row_ptr,
                                                  int* __restrict__ cur) {
    int b = blockIdx.x, t = threadIdx.x;
    int base = b * SCAN_CHUNK + t * 4;
    int v[4];
    int s = 0;
#pragma unroll
    for (int j = 0; j < 4; ++j) {
        int idx = base + j;
        v[j] = (idx < N_NODES) ? deg[idx] : 0;
        s += v[j];
    }
    // inclusive scan of s within wave
    int lane = t & 63, wid = t >> 6;
    int x = s;
#pragma unroll
    for (int off = 1; off < 64; off <<= 1) {
        int y = __shfl_up(x, off);
        if (lane >= off) x += y;
    }
    __shared__ int wsum[4];
    if (lane == 63) wsum[wid] = x;
    __syncthreads();
    int wexcl = 0;
    for (int w = 0; w < wid; ++w) wexcl += wsum[w];
    int run = bsum[b] + wexcl + (x - s);  // exclusive prefix for this thread
#pragma unroll
    for (int j = 0; j < 4; ++j) {
        int idx = base + j;
        if (idx < N_NODES) {
            row_ptr[idx] = run;
            cur[idx] = run;
            run += v[j];
        }
    }
}

__global__ __launch_bounds__(256) void scatter_kernel(const int* __restrict__ src,
                                                      const int* __restrict__ dst,
                                                      int* __restrict__ cur,
                                                      int* __restrict__ col_src) {
    int e = blockIdx.x * 256 + threadIdx.x;
    if (e < N_EDGES) {
        int p = atomicAdd(&cur[dst[e]], 1);
        col_src[p] = src[e];
    }
}

// ---------------------------------------------------------------------------
// Aggregation: out[n] = sum_{e in in-edges(n)} h[src[e]] + h[n]
// one wave per node, lane handles 2 consecutive dims (float2)
// ---------------------------------------------------------------------------
__global__ __launch_bounds__(256) void aggregate(const float* __restrict__ h,
                                                 const int* __restrict__ row_ptr,
                                                 const int* __restrict__ col_src,
                                                 float* __restrict__ out) {
    int wv = (blockIdx.x * 256 + threadIdx.x) >> 6;
    int lane = threadIdx.x & 63;
    if (wv >= N_NODES) return;
    int beg = row_ptr[wv], end = row_ptr[wv + 1];
    float2 acc = make_float2(0.f, 0.f);
    for (int e = beg; e < end; ++e) {
        int s = col_src[e];
        float2 v = *(const float2*)&h[(size_t)s * DIM + lane * 2];
        acc.x += v.x;
        acc.y += v.y;
    }
    float2 hv = *(const float2*)&h[(size_t)wv * DIM + lane * 2];
    acc.x += hv.x;
    acc.y += hv.y;
    *(float2*)&out[(size_t)wv * DIM + lane * 2] = acc;
}

// ---------------------------------------------------------------------------
// GEMM: out[N,128] = op(A)[N,128] @ W[128,128] + bias, optional BN stats /
// BN-pre-transform / post-ReLU.  Tile: 32 rows x 128 cols per block (256 thr).
// LDS: W (64KB) + A tile (16KB) = 80KB -> 2 blocks/CU.
// ---------------------------------------------------------------------------
template <int PRE_BN, int POST_RELU, int STATS>
__global__ __launch_bounds__(256) void gemm128(const float* __restrict__ A,
                                               const float* __restrict__ W,
                                               const float* __restrict__ bias,
                                               float* __restrict__ out,
                                               const float* __restrict__ scale,
                                               const float* __restrict__ shift,
                                               float* __restrict__ bn_sum,
                                               float* __restrict__ bn_sumsq) {
    __shared__ float sW[DIM][DIM];   // 64 KB
    __shared__ float sA[32][DIM];    // 16 KB
    int t = threadIdx.x;
    int row0 = blockIdx.x * 32;

    // stage W (coalesced float4)
#pragma unroll
    for (int i = t * 4; i < DIM * DIM; i += 1024) {
        float4 v = *(const float4*)&W[i];
        *(float4*)&sW[i >> 7][i & 127] = v;
    }
    // stage A tile (with optional BN+ReLU pre-op)
#pragma unroll
    for (int i = t * 4; i < 32 * DIM; i += 1024) {
        int r = i >> 7, c = i & 127;
        float4 v = *(const float4*)&A[(size_t)(row0 + r) * DIM + c];
        if (PRE_BN) {
            v.x = fmaxf(fmaf(v.x, scale[c + 0], shift[c + 0]), 0.f);
            v.y = fmaxf(fmaf(v.y, scale[c + 1], shift[c + 1]), 0.f);
            v.z = fmaxf(fmaf(v.z, scale[c + 2], shift[c + 2]), 0.f);
            v.w = fmaxf(fmaf(v.w, scale[c + 3], shift[c + 3]), 0.f);
        }
        *(float4*)&sA[r][c] = v;
    }
    __syncthreads();

    int tr = t >> 4;   // 0..15 -> rows
    int tc = t & 15;   // 0..15 -> cols
    int r0 = tr * 2, c0 = tc * 8;

    float acc0[8] = {0.f, 0.f, 0.f, 0.f, 0.f, 0.f, 0.f, 0.f};
    float acc1[8] = {0.f, 0.f, 0.f, 0.f, 0.f, 0.f, 0.f, 0.f};

#pragma unroll
    for (int k = 0; k < DIM; k += 4) {
        float4 a0 = *(const float4*)&sA[r0][k];
        float4 a1 = *(const float4*)&sA[r0 + 1][k];
        const float* a0p = &a0.x;
        const float* a1p = &a1.x;
#pragma unroll
        for (int kk = 0; kk < 4; ++kk) {
            float4 w0 = *(const float4*)&sW[k + kk][c0];
            float4 w1 = *(const float4*)&sW[k + kk][c0 + 4];
            float av0 = a0p[kk], av1 = a1p[kk];
            acc0[0] = fmaf(av0, w0.x, acc0[0]);
            acc0[1] = fmaf(av0, w0.y, acc0[1]);
            acc0[2] = fmaf(av0, w0.z, acc0[2]);
            acc0[3] = fmaf(av0, w0.w, acc0[3]);
            acc0[4] = fmaf(av0, w1.x, acc0[4]);
            acc0[5] = fmaf(av0, w1.y, acc0[5]);
            acc0[6] = fmaf(av0, w1.z, acc0[6]);
            acc0[7] = fmaf(av0, w1.w, acc0[7]);
            acc1[0] = fmaf(av1, w0.x, acc1[0]);
            acc1[1] = fmaf(av1, w0.y, acc1[1]);
            acc1[2] = fmaf(av1, w0.z, acc1[2]);
            acc1[3] = fmaf(av1, w0.w, acc1[3]);
            acc1[4] = fmaf(av1, w1.x, acc1[4]);
            acc1[5] = fmaf(av1, w1.y, acc1[5]);
            acc1[6] = fmaf(av1, w1.z, acc1[6]);
            acc1[7] = fmaf(av1, w1.w, acc1[7]);
        }
    }

    float4 bA = *(const float4*)&bias[c0];
    float4 bB = *(const float4*)&bias[c0 + 4];
    float bb[8] = {bA.x, bA.y, bA.z, bA.w, bB.x, bB.y, bB.z, bB.w};

    float s_[8], q_[8];
#pragma unroll
    for (int j = 0; j < 8; ++j) {
        s_[j] = 0.f;
        q_[j] = 0.f;
    }

#pragma unroll
    for (int rr = 0; rr < 2; ++rr) {
        float* accp = rr ? acc1 : acc0;
        float v[8];
#pragma unroll
        for (int j = 0; j < 8; ++j) {
            float val = accp[j] + bb[j];
            if (POST_RELU) val = fmaxf(val, 0.f);
            v[j] = val;
            if (STATS) {
                s_[j] += val;
                q_[j] += val * val;
            }
        }
        int gr = row0 + r0 + rr;
        float4 o0 = make_float4(v[0], v[1], v[2], v[3]);
        float4 o1 = make_float4(v[4], v[5], v[6], v[7]);
        *(float4*)&out[(size_t)gr * DIM + c0] = o0;
        *(float4*)&out[(size_t)gr * DIM + c0 + 4] = o1;
    }

    if (STATS) {
        __syncthreads();  // done reading sA; reuse it as reduction scratch
        float* ls = &sA[0][0];        // 128 floats
        float* lq = &sA[0][0] + DIM;  // 128 floats
        ((float*)sA)[t] = 0.f;        // t in [0,256) clears ls+lq
        __syncthreads();
#pragma unroll
        for (int j = 0; j < 8; ++j) {
            atomicAdd(&ls[c0 + j], s_[j]);
            atomicAdd(&lq[c0 + j], q_[j]);
        }
        __syncthreads();
        if (t < DIM) {
            atomicAdd(&bn_sum[t], ls[t]);
            atomicAdd(&bn_sumsq[t], lq[t]);
        }
    }
}

// ---------------------------------------------------------------------------
// BN finalize: scale/shift per column
// ---------------------------------------------------------------------------
__global__ void bn_finalize(const float* __restrict__ s, const float* __restrict__ q,
                            const float* __restrict__ gamma, const float* __restrict__ beta,
                            float* __restrict__ scale, float* __restrict__ shift) {
    int t = threadIdx.x;
    if (t < DIM) {
        const float invN = 1.0f / (float)N_NODES;
        float mean = s[t] * invN;
        float var = fmaxf(q[t] * invN - mean * mean, 0.f);
        float rs = rsqrtf(var + BN_EPS);
        float sc = gamma[t] * rs;
        scale[t] = sc;
        shift[t] = beta[t] - mean * sc;
    }
}

// ---------------------------------------------------------------------------
// Global add pool: batch is sorted; one wave per 32 consecutive nodes,
// register-accumulate, flush once per graph boundary.
// ---------------------------------------------------------------------------
__global__ __launch_bounds__(256) void pool_kernel(const float* __restrict__ h,
                                                   const int* __restrict__ batch,
                                                   float* __restrict__ out) {
    int wv = (blockIdx.x * 256 + threadIdx.x) >> 6;
    int lane = threadIdx.x & 63;
    int base = wv * 32;
    if (base >= N_NODES) return;
    int end = base + 32;
    if (end > N_NODES) end = N_NODES;
    float2 acc = make_float2(0.f, 0.f);
    int curg = batch[base];
    for (int n = base; n < end; ++n) {
        int g = batch[n];
        if (g != curg) {
            atomicAdd(&out[curg * DIM + lane * 2], acc.x);
            atomicAdd(&out[curg * DIM + lane * 2 + 1], acc.y);
            acc.x = 0.f;
            acc.y = 0.f;
            curg = g;
        }
        float2 v = *(const float2*)&h[(size_t)n * DIM + lane * 2];
        acc.x += v.x;
        acc.y += v.y;
    }
    atomicAdd(&out[curg * DIM + lane * 2], acc.x);
    atomicAdd(&out[curg * DIM + lane * 2 + 1], acc.y);
}

// ---------------------------------------------------------------------------
extern "C" void kernel_launch(void* const* d_in, const int* in_sizes, int n_in,
                              void* d_out, int out_size, void* d_ws, size_t ws_size,
                              hipStream_t stream) {
    const float* x      = (const float*)d_in[0];
    const int*   ei     = (const int*)d_in[1];   // [2, E]: src then dst
    const int*   batch  = (const int*)d_in[2];
    const float* Wn     = (const float*)d_in[3];
    const float* bnode  = (const float*)d_in[4];
    const float* W1     = (const float*)d_in[5];
    const float* b1     = (const float*)d_in[6];
    const float* gamma  = (const float*)d_in[7];
    const float* beta   = (const float*)d_in[8];
    const float* W2     = (const float*)d_in[9];
    const float* b2     = (const float*)d_in[10];
    float* out = (float*)d_out;

    const int* e_src = ei;
    const int* e_dst = ei + N_EDGES;

    // workspace layout
    float* h   = (float*)d_ws;                       // N*D
    float* agg = h + (size_t)N_NODES * DIM;          // N*D
    float* y   = agg + (size_t)N_NODES * DIM;        // N*D
    int* deg     = (int*)(y + (size_t)N_NODES * DIM);
    int* row_ptr = deg + N_NODES;                    // N+1
    int* cur     = row_ptr + N_NODES + 1;            // N
    int* col_src = cur + N_NODES;                    // E
    int* bsum    = col_src + N_EDGES;                // NBLK_SCAN (pad to 128)
    float* bn_sum   = (float*)(bsum + 128);          // 128
    float* bn_sumsq = bn_sum + DIM;                  // 128
    float* bn_scale = bn_sumsq + DIM;                // 128
    float* bn_shift = bn_scale + DIM;                // 128

    const int EB = (N_EDGES + 255) / 256;            // 12500
    const int GEMM_BLOCKS = N_NODES / 32;            // 3125
    const int AGG_BLOCKS = (N_NODES * 64) / 256;     // 25000
    const int POOL_BLOCKS = ((N_NODES + 31) / 32 * 64 + 255) / 256;

    // ---- CSR build (by dst) ----
    hipMemsetAsync(deg, 0, N_NODES * sizeof(int), stream);
    hist_kernel<<<EB, 256, 0, stream>>>(e_dst, deg);
    scan_partial<<<NBLK_SCAN, 256, 0, stream>>>(deg, bsum);
    scan_mid<<<1, 1, 0, stream>>>(bsum, row_ptr);
    scan_final<<<NBLK_SCAN, 256, 0, stream>>>(deg, bsum, row_ptr, cur);
    scatter_kernel<<<EB, 256, 0, stream>>>(e_src, e_dst, cur, col_src);

    // ---- node encoder: h = x @ Wn + bnode ----
    gemm128<0, 0, 0><<<GEMM_BLOCKS, 256, 0, stream>>>(x, Wn, bnode, h, nullptr,
                                                      nullptr, nullptr, nullptr);

    // ---- GIN layers ----
    for (int i = 0; i < N_LAYERS; ++i) {
        aggregate<<<AGG_BLOCKS, 256, 0, stream>>>(h, row_ptr, col_src, agg);
        hipMemsetAsync(bn_sum, 0, 2 * DIM * sizeof(float), stream);
        gemm128<0, 0, 1><<<GEMM_BLOCKS, 256, 0, stream>>>(
            agg, W1 + (size_t)i * DIM * DIM, b1 + i * DIM, y, nullptr, nullptr,
            bn_sum, bn_sumsq);
        bn_finalize<<<1, 128, 0, stream>>>(bn_sum, bn_sumsq, gamma + i * DIM,
                                           beta + i * DIM, bn_scale, bn_shift);
        gemm128<1, 1, 0><<<GEMM_BLOCKS, 256, 0, stream>>>(
            y, W2 + (size_t)i * DIM * DIM, b2 + i * DIM, h, bn_scale, bn_shift,
            nullptr, nullptr);
    }

    // ---- global add pool ----
    hipMemsetAsync(out, 0, NUM_GRAPHS * DIM * sizeof(float), stream);
    pool_kernel<<<POOL_BLOCKS, 256, 0, stream>>>(h, batch, out);
}

// Round 2
// 1201.169 us; speedup vs baseline: 1.8165x; 1.8165x over previous
//
#include <hip/hip_runtime.h>

#define N_NODES 100000
#define M_PAD   100032   // padded to multiple of 64 rows
#define N_EDGES 3200000
#define DIM 128
#define N_LAYERS 3
#define NUM_GRAPHS 128
#define BN_EPS 1e-5f

#define SCAN_CHUNK 1024
#define NBLK_SCAN ((N_NODES + SCAN_CHUNK - 1) / SCAN_CHUNK)  // 98

typedef unsigned int uint32;
typedef unsigned short u16;
typedef __attribute__((ext_vector_type(8))) short bf16x8;
typedef __attribute__((ext_vector_type(4))) float f32x4;

__device__ __forceinline__ float bf2f(u16 u) {
    union { uint32 i; float f; } c;
    c.i = ((uint32)u) << 16;
    return c.f;
}
__device__ __forceinline__ u16 f2bf(float f) {
    union { float f; uint32 i; } c;
    c.f = f;
    uint32 i = c.i;
    return (u16)((i + 0x7FFFu + ((i >> 16) & 1u)) >> 16);
}
__device__ __forceinline__ float lo_bf(uint32 v) {
    union { uint32 i; float f; } c;
    c.i = v << 16;
    return c.f;
}
__device__ __forceinline__ float hi_bf(uint32 v) {
    union { uint32 i; float f; } c;
    c.i = v & 0xFFFF0000u;
    return c.f;
}

// ---------------------------------------------------------------------------
// CSR build: histogram -> scan -> scatter (unchanged from round 1)
// ---------------------------------------------------------------------------
__global__ __launch_bounds__(256) void hist_kernel(const int* __restrict__ dst,
                                                   int* __restrict__ deg) {
    int e = blockIdx.x * 256 + threadIdx.x;
    if (e < N_EDGES) atomicAdd(&deg[dst[e]], 1);
}

__global__ __launch_bounds__(256) void scan_partial(const int* __restrict__ deg,
                                                    int* __restrict__ bsum) {
    int b = blockIdx.x, t = threadIdx.x;
    int base = b * SCAN_CHUNK + t * 4;
    int s = 0;
#pragma unroll
    for (int j = 0; j < 4; ++j) {
        int idx = base + j;
        if (idx < N_NODES) s += deg[idx];
    }
#pragma unroll
    for (int off = 32; off >= 1; off >>= 1) s += __shfl_down(s, off);
    __shared__ int wsum[4];
    int lane = t & 63, wid = t >> 6;
    if (lane == 0) wsum[wid] = s;
    __syncthreads();
    if (t == 0) bsum[b] = wsum[0] + wsum[1] + wsum[2] + wsum[3];
}

__global__ void scan_mid(int* __restrict__ bsum, int* __restrict__ row_ptr) {
    if (threadIdx.x == 0 && blockIdx.x == 0) {
        int excl = 0;
        for (int b = 0; b < NBLK_SCAN; ++b) {
            int v = bsum[b];
            bsum[b] = excl;
            excl += v;
        }
        row_ptr[N_NODES] = excl;
    }
}

__global__ __launch_bounds__(256) void scan_final(const int* __restrict__ deg,
                                                  const int* __restrict__ bsum,
                                                  int* __restrict__ row_ptr,
                                                  int* __restrict__ cur) {
    int b = blockIdx.x, t = threadIdx.x;
    int base = b * SCAN_CHUNK + t * 4;
    int v[4];
    int s = 0;
#pragma unroll
    for (int j = 0; j < 4; ++j) {
        int idx = base + j;
        v[j] = (idx < N_NODES) ? deg[idx] : 0;
        s += v[j];
    }
    int lane = t & 63, wid = t >> 6;
    int x = s;
#pragma unroll
    for (int off = 1; off < 64; off <<= 1) {
        int y = __shfl_up(x, off);
        if (lane >= off) x += y;
    }
    __shared__ int wsum[4];
    if (lane == 63) wsum[wid] = x;
    __syncthreads();
    int wexcl = 0;
    for (int w = 0; w < wid; ++w) wexcl += wsum[w];
    int run = bsum[b] + wexcl + (x - s);
#pragma unroll
    for (int j = 0; j < 4; ++j) {
        int idx = base + j;
        if (idx < N_NODES) {
            row_ptr[idx] = run;
            cur[idx] = run;
            run += v[j];
        }
    }
}

__global__ __launch_bounds__(256) void scatter_kernel(const int* __restrict__ src,
                                                      const int* __restrict__ dst,
                                                      int* __restrict__ cur,
                                                      int* __restrict__ col_src) {
    int e = blockIdx.x * 256 + threadIdx.x;
    if (e < N_EDGES) {
        int p = atomicAdd(&cur[dst[e]], 1);
        col_src[p] = src[e];
    }
}

// ---------------------------------------------------------------------------
// Conversions
// ---------------------------------------------------------------------------
__global__ __launch_bounds__(256) void cvt_x(const float* __restrict__ x,
                                             u16* __restrict__ xb) {
    size_t base = ((size_t)blockIdx.x * 256 + threadIdx.x) * 8;
    if (base >= (size_t)M_PAD * DIM) return;
    int row = (int)(base >> 7);
    union { u16 u[8]; uint4 v; } o;
    if (row < N_NODES) {
        float4 v0 = *(const float4*)&x[base];
        float4 v1 = *(const float4*)&x[base + 4];
        o.u[0] = f2bf(v0.x); o.u[1] = f2bf(v0.y);
        o.u[2] = f2bf(v0.z); o.u[3] = f2bf(v0.w);
        o.u[4] = f2bf(v1.x); o.u[5] = f2bf(v1.y);
        o.u[6] = f2bf(v1.z); o.u[7] = f2bf(v1.w);
    } else {
        o.v = make_uint4(0, 0, 0, 0);
    }
    *(uint4*)&xb[base] = o.v;
}

// W[m][k][n] (f32) -> WT[m][n][k] (bf16), per-matrix transpose
__global__ void cvt_wt(const float* __restrict__ W, u16* __restrict__ WT) {
    int m = blockIdx.x >> 7, n = blockIdx.x & 127, k = threadIdx.x;
    WT[((size_t)m * DIM + n) * DIM + k] = f2bf(W[(size_t)m * DIM * DIM + (size_t)k * DIM + n]);
}

// ---------------------------------------------------------------------------
// Aggregation (bf16 rows): out[n] = sum_{in-edges} h[src] + h[n]
// one wave per node, lane holds dims {2*lane, 2*lane+1}, 256 B/row coalesced
// ---------------------------------------------------------------------------
__global__ __launch_bounds__(256) void aggregate_bf(const u16* __restrict__ h,
                                                    const int* __restrict__ row_ptr,
                                                    const int* __restrict__ col_src,
                                                    u16* __restrict__ agg) {
    int wv = (blockIdx.x * 256 + threadIdx.x) >> 6;
    int lane = threadIdx.x & 63;
    if (wv >= N_NODES) return;
    int beg = row_ptr[wv], end = row_ptr[wv + 1];
    const uint32* h32 = (const uint32*)h;
    uint32 hv = h32[(size_t)wv * 64 + lane];
    float ax = lo_bf(hv), ay = hi_bf(hv);
    int e = beg;
    for (; e + 4 <= end; e += 4) {
        int s0 = col_src[e], s1 = col_src[e + 1], s2 = col_src[e + 2], s3 = col_src[e + 3];
        uint32 v0 = h32[(size_t)s0 * 64 + lane];
        uint32 v1 = h32[(size_t)s1 * 64 + lane];
        uint32 v2 = h32[(size_t)s2 * 64 + lane];
        uint32 v3 = h32[(size_t)s3 * 64 + lane];
        ax += lo_bf(v0); ay += hi_bf(v0);
        ax += lo_bf(v1); ay += hi_bf(v1);
        ax += lo_bf(v2); ay += hi_bf(v2);
        ax += lo_bf(v3); ay += hi_bf(v3);
    }
    for (; e < end; ++e) {
        int s = col_src[e];
        uint32 v = h32[(size_t)s * 64 + lane];
        ax += lo_bf(v); ay += hi_bf(v);
    }
    uint32 o = ((uint32)f2bf(ay) << 16) | (uint32)f2bf(ax);
    ((uint32*)agg)[(size_t)wv * 64 + lane] = o;
}

// ---------------------------------------------------------------------------
// MFMA GEMM: out[M_PAD,128](bf16) = op(A)[M_PAD,128](bf16) @ W + bias
//   WT[n][k] = W[k][n] (bf16).  Block = 256 thr = 4 waves; wave = 16 rows x
//   128 cols (8 col-frags, 4 K-steps of mfma_f32_16x16x32_bf16).
//   A-frag: lane holds A[row0+(l&15)][8*(l>>4) + j + 32*ks]  (contiguous 16B)
//   B-frag: lane holds W[8*(l>>4)+j+32*ks][nf*16+(l&15)] = WT[col][k]  (contig)
//   C/D  : col = l&15, row = (l>>4)*4 + reg   [m89-verified mapping]
// ---------------------------------------------------------------------------
template <int PRE_BN, int POST_RELU, int STATS>
__global__ __launch_bounds__(256) void mfma_gemm(const u16* __restrict__ A,
                                                 const u16* __restrict__ WT,
                                                 const float* __restrict__ bias,
                                                 u16* __restrict__ out,
                                                 const float* __restrict__ scale,
                                                 const float* __restrict__ shift,
                                                 float* __restrict__ bn_sum,
                                                 float* __restrict__ bn_sumsq) {
    int t = threadIdx.x;
    int wid = t >> 6, lane = t & 63;
    int hw = lane >> 4;    // 0..3
    int c = lane & 15;     // 0..15
    int rowA = blockIdx.x * 64 + wid * 16 + c;
    int kb = hw * 8;

    f32x4 acc[8];
#pragma unroll
    for (int i = 0; i < 8; ++i) acc[i] = (f32x4){0.f, 0.f, 0.f, 0.f};

#pragma unroll
    for (int ks = 0; ks < 4; ++ks) {
        int k0 = ks * 32 + kb;
        bf16x8 a = *(const bf16x8*)&A[(size_t)rowA * DIM + k0];
        if (PRE_BN) {
            union { bf16x8 v; u16 u[8]; } ua;
            ua.v = a;
#pragma unroll
            for (int j = 0; j < 8; ++j) {
                float f = bf2f(ua.u[j]);
                f = fmaf(f, scale[k0 + j], shift[k0 + j]);
                f = fmaxf(f, 0.f);
                ua.u[j] = f2bf(f);
            }
            a = ua.v;
        }
#pragma unroll
        for (int nf = 0; nf < 8; ++nf) {
            bf16x8 b = *(const bf16x8*)&WT[(size_t)(nf * 16 + c) * DIM + k0];
            acc[nf] = __builtin_amdgcn_mfma_f32_16x16x32_bf16(a, b, acc[nf], 0, 0, 0);
        }
    }

    int rbase = blockIdx.x * 64 + wid * 16 + hw * 4;
    float s_[8], q_[8];
#pragma unroll
    for (int nf = 0; nf < 8; ++nf) {
        float bv = bias[nf * 16 + c];
        float ss = 0.f, qq = 0.f;
#pragma unroll
        for (int r = 0; r < 4; ++r) {
            float v = acc[nf][r] + bv;
            if (POST_RELU) v = fmaxf(v, 0.f);
            out[(size_t)(rbase + r) * DIM + nf * 16 + c] = f2bf(v);
            if (STATS) {
                float m = (rbase + r < N_NODES) ? v : 0.f;
                ss += m;
                qq += m * m;
            }
        }
        s_[nf] = ss;
        q_[nf] = qq;
    }

    if (STATS) {
        __shared__ float ls[4][DIM];
        __shared__ float lq[4][DIM];
#pragma unroll
        for (int nf = 0; nf < 8; ++nf) {
            s_[nf] += __shfl_xor(s_[nf], 16);
            s_[nf] += __shfl_xor(s_[nf], 32);
            q_[nf] += __shfl_xor(q_[nf], 16);
            q_[nf] += __shfl_xor(q_[nf], 32);
        }
        if (lane < 16) {
#pragma unroll
            for (int nf = 0; nf < 8; ++nf) {
                ls[wid][nf * 16 + c] = s_[nf];
                lq[wid][nf * 16 + c] = q_[nf];
            }
        }
        __syncthreads();
        if (t < DIM) {
            float S = ls[0][t] + ls[1][t] + ls[2][t] + ls[3][t];
            float Q = lq[0][t] + lq[1][t] + lq[2][t] + lq[3][t];
            atomicAdd(&bn_sum[t], S);
            atomicAdd(&bn_sumsq[t], Q);
        }
    }
}

// ---------------------------------------------------------------------------
__global__ void bn_finalize(const float* __restrict__ s, const float* __restrict__ q,
                            const float* __restrict__ gamma, const float* __restrict__ beta,
                            float* __restrict__ scale, float* __restrict__ shift) {
    int t = threadIdx.x;
    if (t < DIM) {
        const float invN = 1.0f / (float)N_NODES;
        float mean = s[t] * invN;
        float var = fmaxf(q[t] * invN - mean * mean, 0.f);
        float rs = rsqrtf(var + BN_EPS);
        float sc = gamma[t] * rs;
        scale[t] = sc;
        shift[t] = beta[t] - mean * sc;
    }
}

// ---------------------------------------------------------------------------
// Global add pool (bf16 in, f32 out); batch sorted, one wave per 32 nodes
// ---------------------------------------------------------------------------
__global__ __launch_bounds__(256) void pool_bf(const u16* __restrict__ h,
                                               const int* __restrict__ batch,
                                               float* __restrict__ out) {
    int wv = (blockIdx.x * 256 + threadIdx.x) >> 6;
    int lane = threadIdx.x & 63;
    int base = wv * 32;
    if (base >= N_NODES) return;
    int end = base + 32;
    if (end > N_NODES) end = N_NODES;
    const uint32* h32 = (const uint32*)h;
    float ax = 0.f, ay = 0.f;
    int curg = batch[base];
    for (int n = base; n < end; ++n) {
        int g = batch[n];
        if (g != curg) {
            atomicAdd(&out[curg * DIM + lane * 2], ax);
            atomicAdd(&out[curg * DIM + lane * 2 + 1], ay);
            ax = 0.f;
            ay = 0.f;
            curg = g;
        }
        uint32 v = h32[(size_t)n * 64 + lane];
        ax += lo_bf(v);
        ay += hi_bf(v);
    }
    atomicAdd(&out[curg * DIM + lane * 2], ax);
    atomicAdd(&out[curg * DIM + lane * 2 + 1], ay);
}

// ---------------------------------------------------------------------------
extern "C" void kernel_launch(void* const* d_in, const int* in_sizes, int n_in,
                              void* d_out, int out_size, void* d_ws, size_t ws_size,
                              hipStream_t stream) {
    const float* x     = (const float*)d_in[0];
    const int*   ei    = (const int*)d_in[1];
    const int*   batch = (const int*)d_in[2];
    const float* Wn    = (const float*)d_in[3];
    const float* bnode = (const float*)d_in[4];
    const float* W1    = (const float*)d_in[5];
    const float* b1    = (const float*)d_in[6];
    const float* gamma = (const float*)d_in[7];
    const float* beta  = (const float*)d_in[8];
    const float* W2    = (const float*)d_in[9];
    const float* b2    = (const float*)d_in[10];
    float* out = (float*)d_out;

    const int* e_src = ei;
    const int* e_dst = ei + N_EDGES;

    // workspace layout (16B-aligned blocks)
    const size_t MD = (size_t)M_PAD * DIM;  // 12,804,096 elements
    u16* xb  = (u16*)d_ws;
    u16* h   = xb + MD;
    u16* agg = h + MD;
    u16* y   = agg + MD;
    u16* WTn = y + MD;           // 128*128
    u16* WT1 = WTn + DIM * DIM;  // 3*128*128
    u16* WT2 = WT1 + 3 * DIM * DIM;
    int* deg     = (int*)(WT2 + 3 * DIM * DIM);
    int* row_ptr = deg + N_NODES;
    int* cur     = row_ptr + N_NODES + 1;
    int* col_src = cur + N_NODES;
    int* bsum    = col_src + N_EDGES;
    float* bn_sum   = (float*)(bsum + 128);
    float* bn_sumsq = bn_sum + DIM;
    float* bn_scale = bn_sumsq + DIM;
    float* bn_shift = bn_scale + DIM;

    const int EB = (N_EDGES + 255) / 256;          // 12500
    const int GEMM_BLOCKS = M_PAD / 64;            // 1563
    const int AGG_BLOCKS = (N_NODES * 64) / 256;   // 25000
    const int POOL_BLOCKS = (((N_NODES + 31) / 32) * 64 + 255) / 256;
    const int CVT_BLOCKS = (int)(MD / 8 / 256);    // 6252 exact

    // ---- CSR build (by dst) ----
    hipMemsetAsync(deg, 0, N_NODES * sizeof(int), stream);
    hist_kernel<<<EB, 256, 0, stream>>>(e_dst, deg);
    scan_partial<<<NBLK_SCAN, 256, 0, stream>>>(deg, bsum);
    scan_mid<<<1, 1, 0, stream>>>(bsum, row_ptr);
    scan_final<<<NBLK_SCAN, 256, 0, stream>>>(deg, bsum, row_ptr, cur);
    scatter_kernel<<<EB, 256, 0, stream>>>(e_src, e_dst, cur, col_src);

    // ---- conversions ----
    cvt_x<<<CVT_BLOCKS, 256, 0, stream>>>(x, xb);
    cvt_wt<<<1 * DIM, DIM, 0, stream>>>(Wn, WTn);
    cvt_wt<<<3 * DIM, DIM, 0, stream>>>(W1, WT1);
    cvt_wt<<<3 * DIM, DIM, 0, stream>>>(W2, WT2);
    // zero agg pad rows once per call (aggregate only writes rows < N_NODES)
    hipMemsetAsync(agg + (size_t)N_NODES * DIM, 0, (M_PAD - N_NODES) * DIM * sizeof(u16), stream);

    // ---- node encoder: h = x @ Wn + bnode ----
    mfma_gemm<0, 0, 0><<<GEMM_BLOCKS, 256, 0, stream>>>(xb, WTn, bnode, h, nullptr,
                                                        nullptr, nullptr, nullptr);

    // ---- GIN layers ----
    for (int i = 0; i < N_LAYERS; ++i) {
        aggregate_bf<<<AGG_BLOCKS, 256, 0, stream>>>(h, row_ptr, col_src, agg);
        hipMemsetAsync(bn_sum, 0, 2 * DIM * sizeof(float), stream);
        mfma_gemm<0, 0, 1><<<GEMM_BLOCKS, 256, 0, stream>>>(
            agg, WT1 + (size_t)i * DIM * DIM, b1 + i * DIM, y, nullptr, nullptr,
            bn_sum, bn_sumsq);
        bn_finalize<<<1, 128, 0, stream>>>(bn_sum, bn_sumsq, gamma + i * DIM,
                                           beta + i * DIM, bn_scale, bn_shift);
        mfma_gemm<1, 1, 0><<<GEMM_BLOCKS, 256, 0, stream>>>(
            y, WT2 + (size_t)i * DIM * DIM, b2 + i * DIM, h, bn_scale, bn_shift,
            nullptr, nullptr);
    }

    // ---- global add pool ----
    hipMemsetAsync(out, 0, NUM_GRAPHS * DIM * sizeof(float), stream);
    pool_bf<<<POOL_BLOCKS, 256, 0, stream>>>(h, batch, out);
}

// Round 3
// 878.004 us; speedup vs baseline: 2.4851x; 1.3681x over previous
//
#include <hip/hip_runtime.h>

#define N_NODES 100000
#define M_PAD   100032   // padded to multiple of 64 rows
#define N_EDGES 3200000
#define DIM 128
#define N_LAYERS 3
#define NUM_GRAPHS 128
#define BN_EPS 1e-5f

// ---- binned CSR build parameters ----
#define DST_SHIFT 7
#define BUCKET_NODES 128                                   // nodes per bucket
#define N_BUCKETS ((N_NODES + BUCKET_NODES - 1) / BUCKET_NODES)  // 782
#define BUCKET_CAP 4864                                    // avg 4092 + 12 sigma
#define EDGES_PER_BLOCK 4096
#define BIN_BLOCKS ((N_EDGES + EDGES_PER_BLOCK - 1) / EDGES_PER_BLOCK)  // 782
#define N_BANDS 64                                         // used: (src>>11) in [0,49)

typedef unsigned int uint32;
typedef unsigned short u16;
typedef __attribute__((ext_vector_type(8))) short bf16x8;
typedef __attribute__((ext_vector_type(4))) float f32x4;

__device__ __forceinline__ float bf2f(u16 u) {
    union { uint32 i; float f; } c;
    c.i = ((uint32)u) << 16;
    return c.f;
}
__device__ __forceinline__ u16 f2bf(float f) {
    union { float f; uint32 i; } c;
    c.f = f;
    uint32 i = c.i;
    return (u16)((i + 0x7FFFu + ((i >> 16) & 1u)) >> 16);
}
__device__ __forceinline__ float lo_bf(uint32 v) {
    union { uint32 i; float f; } c;
    c.i = v << 16;
    return c.f;
}
__device__ __forceinline__ float hi_bf(uint32 v) {
    union { uint32 i; float f; } c;
    c.i = v & 0xFFFF0000u;
    return c.f;
}

// ---------------------------------------------------------------------------
// Stage A: bin edges by dst bucket. packed = src | (dst&127)<<17
// ---------------------------------------------------------------------------
__global__ __launch_bounds__(256) void bin_by_dst(const int* __restrict__ src,
                                                  const int* __restrict__ dst,
                                                  int* __restrict__ gcur,
                                                  uint32* __restrict__ packed) {
    __shared__ int cnt[N_BUCKETS];
    __shared__ int base[N_BUCKETS];
    int t = threadIdx.x;
    for (int i = t; i < N_BUCKETS; i += 256) cnt[i] = 0;
    __syncthreads();

    int e0 = blockIdx.x * EDGES_PER_BLOCK + t * 16;
    uint32 pk[16];
    int bkt[16];
    int rnk[16];
#pragma unroll
    for (int j = 0; j < 16; ++j) {
        int e = e0 + j;
        if (e < N_EDGES) {
            int d = dst[e];
            int sv = src[e];
            int b = d >> DST_SHIFT;
            bkt[j] = b;
            rnk[j] = atomicAdd(&cnt[b], 1);
            pk[j] = (uint32)sv | ((uint32)(d & (BUCKET_NODES - 1)) << 17);
        } else {
            bkt[j] = -1;
            rnk[j] = 0;
            pk[j] = 0;
        }
    }
    __syncthreads();
    for (int i = t; i < N_BUCKETS; i += 256) {
        int c = cnt[i];
        base[i] = c ? atomicAdd(&gcur[i], c) : 0;
    }
    __syncthreads();
#pragma unroll
    for (int j = 0; j < 16; ++j) {
        if (bkt[j] >= 0) {
            int pos = base[bkt[j]] + rnk[j];
            if (pos < BUCKET_CAP)
                packed[(size_t)bkt[j] * BUCKET_CAP + pos] = pk[j];
        }
    }
}

// ---------------------------------------------------------------------------
// exclusive scan over bucket totals -> output bases; also row_ptr[N] = E
// ---------------------------------------------------------------------------
__global__ void scan_buckets(const int* __restrict__ gcur, int* __restrict__ obase,
                             int* __restrict__ row_ptr) {
    __shared__ int s[N_BUCKETS];
    int t = threadIdx.x;
    for (int i = t; i < N_BUCKETS; i += 256) {
        int c = gcur[i];
        s[i] = (c > BUCKET_CAP) ? BUCKET_CAP : c;
    }
    __syncthreads();
    if (t == 0) {
        int run = 0;
        for (int i = 0; i < N_BUCKETS; ++i) {
            int c = s[i];
            s[i] = run;
            run += c;
        }
        row_ptr[N_NODES] = run;
    }
    __syncthreads();
    for (int i = t; i < N_BUCKETS; i += 256) obase[i] = s[i];
}

// ---------------------------------------------------------------------------
// Stage B: per bucket — per-node offsets (row_ptr), band-sort by src>>11,
// then place into the bucket's contiguous col_src window (L2-resident).
// ---------------------------------------------------------------------------
__global__ __launch_bounds__(256) void build_buckets(const uint32* __restrict__ packed,
                                                     const int* __restrict__ gcur,
                                                     const int* __restrict__ obase_arr,
                                                     int* __restrict__ row_ptr,
                                                     int* __restrict__ col_src) {
    __shared__ uint32 ed[BUCKET_CAP];
    __shared__ uint32 ed2[BUCKET_CAP];
    __shared__ int bandcur[N_BANDS];
    __shared__ int ncnt[BUCKET_NODES];
    __shared__ int ncur[BUCKET_NODES];
    int b = blockIdx.x, t = threadIdx.x;
    int cnt = gcur[b];
    if (cnt > BUCKET_CAP) cnt = BUCKET_CAP;
    int obase = obase_arr[b];
    int n0 = b * BUCKET_NODES;

    if (t < N_BANDS) bandcur[t] = 0;
    if (t < BUCKET_NODES) ncnt[t] = 0;
    __syncthreads();

    const uint32* reg = packed + (size_t)b * BUCKET_CAP;
    for (int i = t; i < cnt; i += 256) {
        uint32 v = reg[i];
        ed[i] = v;
        atomicAdd(&bandcur[(v & 0x1FFFFu) >> 11], 1);
        atomicAdd(&ncnt[v >> 17], 1);
    }
    __syncthreads();

    // exclusive scan of band counts (49 values, serial)
    if (t == 0) {
        int run = 0;
        for (int w = 0; w < N_BANDS; ++w) {
            int c = bandcur[w];
            bandcur[w] = run;
            run += c;
        }
    }
    // inclusive scan of node counts (Hillis-Steele over 128)
    int myc = (t < BUCKET_NODES) ? ncnt[t] : 0;
    if (t < BUCKET_NODES) ncur[t] = myc;
    __syncthreads();
    for (int off = 1; off < BUCKET_NODES; off <<= 1) {
        int v = 0;
        if (t < BUCKET_NODES && t >= off) v = ncur[t - off];
        __syncthreads();
        if (t < BUCKET_NODES) ncur[t] += v;
        __syncthreads();
    }
    if (t < BUCKET_NODES) {
        int excl = ncur[t] - myc;
        ncur[t] = excl;
        int gn = n0 + t;
        if (gn < N_NODES) row_ptr[gn] = obase + excl;
    }
    __syncthreads();

    // counting sort by src band
    for (int i = t; i < cnt; i += 256) {
        uint32 v = ed[i];
        int p = atomicAdd(&bandcur[(v & 0x1FFFFu) >> 11], 1);
        ed2[p] = v;
    }
    __syncthreads();

    // place into per-node slots (band order preserved up to ~256-entry noise)
    for (int i = t; i < cnt; i += 256) {
        uint32 v = ed2[i];
        int slot = atomicAdd(&ncur[v >> 17], 1);
        col_src[obase + slot] = (int)(v & 0x1FFFFu);
    }
}

// ---------------------------------------------------------------------------
// Conversions
// ---------------------------------------------------------------------------
__global__ __launch_bounds__(256) void cvt_x(const float* __restrict__ x,
                                             u16* __restrict__ xb) {
    size_t base = ((size_t)blockIdx.x * 256 + threadIdx.x) * 8;
    if (base >= (size_t)M_PAD * DIM) return;
    int row = (int)(base >> 7);
    union { u16 u[8]; uint4 v; } o;
    if (row < N_NODES) {
        float4 v0 = *(const float4*)&x[base];
        float4 v1 = *(const float4*)&x[base + 4];
        o.u[0] = f2bf(v0.x); o.u[1] = f2bf(v0.y);
        o.u[2] = f2bf(v0.z); o.u[3] = f2bf(v0.w);
        o.u[4] = f2bf(v1.x); o.u[5] = f2bf(v1.y);
        o.u[6] = f2bf(v1.z); o.u[7] = f2bf(v1.w);
    } else {
        o.v = make_uint4(0, 0, 0, 0);
    }
    *(uint4*)&xb[base] = o.v;
}

// W[m][k][n] (f32) -> WT[m][n][k] (bf16)
__global__ void cvt_wt(const float* __restrict__ W, u16* __restrict__ WT) {
    int m = blockIdx.x >> 7, n = blockIdx.x & 127, k = threadIdx.x;
    WT[((size_t)m * DIM + n) * DIM + k] = f2bf(W[(size_t)m * DIM * DIM + (size_t)k * DIM + n]);
}

// ---------------------------------------------------------------------------
// Aggregation (bf16 rows): agg[n] = sum_{in-edges} h[src] + h[n]
// ---------------------------------------------------------------------------
__global__ __launch_bounds__(256) void aggregate_bf(const u16* __restrict__ h,
                                                    const int* __restrict__ row_ptr,
                                                    const int* __restrict__ col_src,
                                                    u16* __restrict__ agg) {
    int wv = (blockIdx.x * 256 + threadIdx.x) >> 6;
    int lane = threadIdx.x & 63;
    if (wv >= N_NODES) return;
    int beg = row_ptr[wv], end = row_ptr[wv + 1];
    const uint32* h32 = (const uint32*)h;
    uint32 hv = h32[(size_t)wv * 64 + lane];
    float ax = lo_bf(hv), ay = hi_bf(hv);
    int e = beg;
    for (; e + 4 <= end; e += 4) {
        int s0 = col_src[e], s1 = col_src[e + 1], s2 = col_src[e + 2], s3 = col_src[e + 3];
        uint32 v0 = h32[(size_t)s0 * 64 + lane];
        uint32 v1 = h32[(size_t)s1 * 64 + lane];
        uint32 v2 = h32[(size_t)s2 * 64 + lane];
        uint32 v3 = h32[(size_t)s3 * 64 + lane];
        ax += lo_bf(v0); ay += hi_bf(v0);
        ax += lo_bf(v1); ay += hi_bf(v1);
        ax += lo_bf(v2); ay += hi_bf(v2);
        ax += lo_bf(v3); ay += hi_bf(v3);
    }
    for (; e < end; ++e) {
        int s = col_src[e];
        uint32 v = h32[(size_t)s * 64 + lane];
        ax += lo_bf(v); ay += hi_bf(v);
    }
    uint32 o = ((uint32)f2bf(ay) << 16) | (uint32)f2bf(ax);
    ((uint32*)agg)[(size_t)wv * 64 + lane] = o;
}

// ---------------------------------------------------------------------------
// MFMA GEMM (unchanged from round 2): out = op(A) @ W + bias
// ---------------------------------------------------------------------------
template <int PRE_BN, int POST_RELU, int STATS>
__global__ __launch_bounds__(256) void mfma_gemm(const u16* __restrict__ A,
                                                 const u16* __restrict__ WT,
                                                 const float* __restrict__ bias,
                                                 u16* __restrict__ out,
                                                 const float* __restrict__ scale,
                                                 const float* __restrict__ shift,
                                                 float* __restrict__ bn_sum,
                                                 float* __restrict__ bn_sumsq) {
    int t = threadIdx.x;
    int wid = t >> 6, lane = t & 63;
    int hw = lane >> 4;
    int c = lane & 15;
    int rowA = blockIdx.x * 64 + wid * 16 + c;
    int kb = hw * 8;

    f32x4 acc[8];
#pragma unroll
    for (int i = 0; i < 8; ++i) acc[i] = (f32x4){0.f, 0.f, 0.f, 0.f};

#pragma unroll
    for (int ks = 0; ks < 4; ++ks) {
        int k0 = ks * 32 + kb;
        bf16x8 a = *(const bf16x8*)&A[(size_t)rowA * DIM + k0];
        if (PRE_BN) {
            union { bf16x8 v; u16 u[8]; } ua;
            ua.v = a;
#pragma unroll
            for (int j = 0; j < 8; ++j) {
                float f = bf2f(ua.u[j]);
                f = fmaf(f, scale[k0 + j], shift[k0 + j]);
                f = fmaxf(f, 0.f);
                ua.u[j] = f2bf(f);
            }
            a = ua.v;
        }
#pragma unroll
        for (int nf = 0; nf < 8; ++nf) {
            bf16x8 b = *(const bf16x8*)&WT[(size_t)(nf * 16 + c) * DIM + k0];
            acc[nf] = __builtin_amdgcn_mfma_f32_16x16x32_bf16(a, b, acc[nf], 0, 0, 0);
        }
    }

    int rbase = blockIdx.x * 64 + wid * 16 + hw * 4;
    float s_[8], q_[8];
#pragma unroll
    for (int nf = 0; nf < 8; ++nf) {
        float bv = bias[nf * 16 + c];
        float ss = 0.f, qq = 0.f;
#pragma unroll
        for (int r = 0; r < 4; ++r) {
            float v = acc[nf][r] + bv;
            if (POST_RELU) v = fmaxf(v, 0.f);
            out[(size_t)(rbase + r) * DIM + nf * 16 + c] = f2bf(v);
            if (STATS) {
                float m = (rbase + r < N_NODES) ? v : 0.f;
                ss += m;
                qq += m * m;
            }
        }
        s_[nf] = ss;
        q_[nf] = qq;
    }

    if (STATS) {
        __shared__ float ls[4][DIM];
        __shared__ float lq[4][DIM];
#pragma unroll
        for (int nf = 0; nf < 8; ++nf) {
            s_[nf] += __shfl_xor(s_[nf], 16);
            s_[nf] += __shfl_xor(s_[nf], 32);
            q_[nf] += __shfl_xor(q_[nf], 16);
            q_[nf] += __shfl_xor(q_[nf], 32);
        }
        if (lane < 16) {
#pragma unroll
            for (int nf = 0; nf < 8; ++nf) {
                ls[wid][nf * 16 + c] = s_[nf];
                lq[wid][nf * 16 + c] = q_[nf];
            }
        }
        __syncthreads();
        if (t < DIM) {
            float S = ls[0][t] + ls[1][t] + ls[2][t] + ls[3][t];
            float Q = lq[0][t] + lq[1][t] + lq[2][t] + lq[3][t];
            atomicAdd(&bn_sum[t], S);
            atomicAdd(&bn_sumsq[t], Q);
        }
    }
}

// ---------------------------------------------------------------------------
__global__ void bn_finalize(const float* __restrict__ s, const float* __restrict__ q,
                            const float* __restrict__ gamma, const float* __restrict__ beta,
                            float* __restrict__ scale, float* __restrict__ shift) {
    int t = threadIdx.x;
    if (t < DIM) {
        const float invN = 1.0f / (float)N_NODES;
        float mean = s[t] * invN;
        float var = fmaxf(q[t] * invN - mean * mean, 0.f);
        float rs = rsqrtf(var + BN_EPS);
        float sc = gamma[t] * rs;
        scale[t] = sc;
        shift[t] = beta[t] - mean * sc;
    }
}

// ---------------------------------------------------------------------------
// Global add pool (bf16 in, f32 out); batch sorted
// ---------------------------------------------------------------------------
__global__ __launch_bounds__(256) void pool_bf(const u16* __restrict__ h,
                                               const int* __restrict__ batch,
                                               float* __restrict__ out) {
    int wv = (blockIdx.x * 256 + threadIdx.x) >> 6;
    int lane = threadIdx.x & 63;
    int base = wv * 32;
    if (base >= N_NODES) return;
    int end = base + 32;
    if (end > N_NODES) end = N_NODES;
    const uint32* h32 = (const uint32*)h;
    float ax = 0.f, ay = 0.f;
    int curg = batch[base];
    for (int n = base; n < end; ++n) {
        int g = batch[n];
        if (g != curg) {
            atomicAdd(&out[curg * DIM + lane * 2], ax);
            atomicAdd(&out[curg * DIM + lane * 2 + 1], ay);
            ax = 0.f;
            ay = 0.f;
            curg = g;
        }
        uint32 v = h32[(size_t)n * 64 + lane];
        ax += lo_bf(v);
        ay += hi_bf(v);
    }
    atomicAdd(&out[curg * DIM + lane * 2], ax);
    atomicAdd(&out[curg * DIM + lane * 2 + 1], ay);
}

// ---------------------------------------------------------------------------
extern "C" void kernel_launch(void* const* d_in, const int* in_sizes, int n_in,
                              void* d_out, int out_size, void* d_ws, size_t ws_size,
                              hipStream_t stream) {
    const float* x     = (const float*)d_in[0];
    const int*   ei    = (const int*)d_in[1];
    const int*   batch = (const int*)d_in[2];
    const float* Wn    = (const float*)d_in[3];
    const float* bnode = (const float*)d_in[4];
    const float* W1    = (const float*)d_in[5];
    const float* b1    = (const float*)d_in[6];
    const float* gamma = (const float*)d_in[7];
    const float* beta  = (const float*)d_in[8];
    const float* W2    = (const float*)d_in[9];
    const float* b2    = (const float*)d_in[10];
    float* out = (float*)d_out;

    const int* e_src = ei;
    const int* e_dst = ei + N_EDGES;

    // workspace layout
    const size_t MD = (size_t)M_PAD * DIM;
    u16* xb  = (u16*)d_ws;
    u16* h   = xb + MD;
    u16* agg = h + MD;
    u16* y   = agg + MD;
    u16* WTn = y + MD;
    u16* WT1 = WTn + DIM * DIM;
    u16* WT2 = WT1 + 3 * DIM * DIM;
    int* row_ptr = (int*)(WT2 + 3 * DIM * DIM);
    int* col_src = row_ptr + N_NODES + 1;
    int* gcur    = col_src + N_EDGES;
    int* obase   = gcur + N_BUCKETS;
    float* bn_sum   = (float*)(obase + N_BUCKETS);
    float* bn_sumsq = bn_sum + DIM;
    float* bn_scale = bn_sumsq + DIM;
    float* bn_shift = bn_scale + DIM;
    // packed edge regions alias y: only used during CSR build, before any GEMM
    uint32* packed = (uint32*)y;   // N_BUCKETS*BUCKET_CAP u32 = 15.2MB <= 25.6MB

    const int GEMM_BLOCKS = M_PAD / 64;
    const int AGG_BLOCKS = (N_NODES * 64) / 256;
    const int POOL_BLOCKS = (((N_NODES + 31) / 32) * 64 + 255) / 256;
    const int CVT_BLOCKS = (int)(MD / 8 / 256);

    // ---- CSR build (binned two-stage counting sort) ----
    hipMemsetAsync(gcur, 0, N_BUCKETS * sizeof(int), stream);
    bin_by_dst<<<BIN_BLOCKS, 256, 0, stream>>>(e_src, e_dst, gcur, packed);
    scan_buckets<<<1, 256, 0, stream>>>(gcur, obase, row_ptr);
    build_buckets<<<N_BUCKETS, 256, 0, stream>>>(packed, gcur, obase, row_ptr, col_src);

    // ---- conversions ----
    cvt_x<<<CVT_BLOCKS, 256, 0, stream>>>(x, xb);
    cvt_wt<<<1 * DIM, DIM, 0, stream>>>(Wn, WTn);
    cvt_wt<<<3 * DIM, DIM, 0, stream>>>(W1, WT1);
    cvt_wt<<<3 * DIM, DIM, 0, stream>>>(W2, WT2);
    hipMemsetAsync(agg + (size_t)N_NODES * DIM, 0, (M_PAD - N_NODES) * DIM * sizeof(u16), stream);

    // ---- node encoder ----
    mfma_gemm<0, 0, 0><<<GEMM_BLOCKS, 256, 0, stream>>>(xb, WTn, bnode, h, nullptr,
                                                        nullptr, nullptr, nullptr);

    // ---- GIN layers ----
    for (int i = 0; i < N_LAYERS; ++i) {
        aggregate_bf<<<AGG_BLOCKS, 256, 0, stream>>>(h, row_ptr, col_src, agg);
        hipMemsetAsync(bn_sum, 0, 2 * DIM * sizeof(float), stream);
        mfma_gemm<0, 0, 1><<<GEMM_BLOCKS, 256, 0, stream>>>(
            agg, WT1 + (size_t)i * DIM * DIM, b1 + i * DIM, y, nullptr, nullptr,
            bn_sum, bn_sumsq);
        bn_finalize<<<1, 128, 0, stream>>>(bn_sum, bn_sumsq, gamma + i * DIM,
                                           beta + i * DIM, bn_scale, bn_shift);
        mfma_gemm<1, 1, 0><<<GEMM_BLOCKS, 256, 0, stream>>>(
            y, WT2 + (size_t)i * DIM * DIM, b2 + i * DIM, h, bn_scale, bn_shift,
            nullptr, nullptr);
    }

    // ---- global add pool ----
    hipMemsetAsync(out, 0, NUM_GRAPHS * DIM * sizeof(float), stream);
    pool_bf<<<POOL_BLOCKS, 256, 0, stream>>>(h, batch, out);
}

// Round 4
// 858.542 us; speedup vs baseline: 2.5415x; 1.0227x over previous
//
#include <hip/hip_runtime.h>

#define N_NODES 100000
#define M_PAD   100032   // padded to multiple of 64 rows
#define N_EDGES 3200000
#define DIM 128
#define N_LAYERS 3
#define NUM_GRAPHS 128
#define BN_EPS 1e-5f

// ---- binned CSR build parameters ----
#define DST_SHIFT 7
#define BUCKET_NODES 128
#define N_BUCKETS ((N_NODES + BUCKET_NODES - 1) / BUCKET_NODES)  // 782
#define BUCKET_CAP 4864
#define EDGES_PER_BLOCK 16384
#define BIN_BLOCKS ((N_EDGES + EDGES_PER_BLOCK - 1) / EDGES_PER_BLOCK)  // 196
#define N_BANDS 64   // used: (src>>11) in [0,49)

typedef unsigned int uint32;
typedef unsigned short u16;
typedef __attribute__((ext_vector_type(8))) short bf16x8;
typedef __attribute__((ext_vector_type(4))) float f32x4;

__device__ __forceinline__ float bf2f(u16 u) {
    union { uint32 i; float f; } c;
    c.i = ((uint32)u) << 16;
    return c.f;
}
__device__ __forceinline__ u16 f2bf(float f) {
    union { float f; uint32 i; } c;
    c.f = f;
    uint32 i = c.i;
    return (u16)((i + 0x7FFFu + ((i >> 16) & 1u)) >> 16);
}
__device__ __forceinline__ float lo_bf(uint32 v) {
    union { uint32 i; float f; } c;
    c.i = v << 16;
    return c.f;
}
__device__ __forceinline__ float hi_bf(uint32 v) {
    union { uint32 i; float f; } c;
    c.i = v & 0xFFFF0000u;
    return c.f;
}
__device__ __forceinline__ uint32 pack_bf2(float a, float b) {
    return ((uint32)f2bf(b) << 16) | (uint32)f2bf(a);
}

// ---------------------------------------------------------------------------
// Stage A: bin edges by dst bucket (2-pass, coalesced). packed = src|(dst&127)<<17
// ---------------------------------------------------------------------------
__global__ __launch_bounds__(256) void bin_by_dst(const int* __restrict__ src,
                                                  const int* __restrict__ dst,
                                                  int* __restrict__ gcur,
                                                  uint32* __restrict__ packed) {
    __shared__ int cnt[N_BUCKETS];
    __shared__ int cur[N_BUCKETS];
    int t = threadIdx.x;
    int e0 = blockIdx.x * EDGES_PER_BLOCK;
    for (int i = t; i < N_BUCKETS; i += 256) cnt[i] = 0;
    __syncthreads();

    // pass 1: count (coalesced)
    for (int j = 0; j < EDGES_PER_BLOCK / 256; ++j) {
        int e = e0 + j * 256 + t;
        if (e < N_EDGES) atomicAdd(&cnt[dst[e] >> DST_SHIFT], 1);
    }
    __syncthreads();
    // reserve global ranges
    for (int i = t; i < N_BUCKETS; i += 256) {
        int c = cnt[i];
        cur[i] = c ? atomicAdd(&gcur[i], c) : 0;
    }
    __syncthreads();
    // pass 2: place (coalesced reads, short contiguous runs per bucket)
    for (int j = 0; j < EDGES_PER_BLOCK / 256; ++j) {
        int e = e0 + j * 256 + t;
        if (e < N_EDGES) {
            int d = dst[e];
            int b = d >> DST_SHIFT;
            int pos = atomicAdd(&cur[b], 1);
            if (pos < BUCKET_CAP)
                packed[(size_t)b * BUCKET_CAP + pos] =
                    (uint32)src[e] | ((uint32)(d & (BUCKET_NODES - 1)) << 17);
        }
    }
}

// ---------------------------------------------------------------------------
__global__ void scan_buckets(const int* __restrict__ gcur, int* __restrict__ obase,
                             int* __restrict__ row_ptr) {
    __shared__ int s[N_BUCKETS];
    int t = threadIdx.x;
    for (int i = t; i < N_BUCKETS; i += 256) {
        int c = gcur[i];
        s[i] = (c > BUCKET_CAP) ? BUCKET_CAP : c;
    }
    __syncthreads();
    if (t == 0) {
        int run = 0;
        for (int i = 0; i < N_BUCKETS; ++i) {
            int c = s[i];
            s[i] = run;
            run += c;
        }
        row_ptr[N_NODES] = run;
    }
    __syncthreads();
    for (int i = t; i < N_BUCKETS; i += 256) obase[i] = s[i];
}

// ---------------------------------------------------------------------------
// Stage B: per bucket — row_ptr, band-sort by src>>11, place into col_src
// ---------------------------------------------------------------------------
__global__ __launch_bounds__(256) void build_buckets(const uint32* __restrict__ packed,
                                                     const int* __restrict__ gcur,
                                                     const int* __restrict__ obase_arr,
                                                     int* __restrict__ row_ptr,
                                                     int* __restrict__ col_src) {
    __shared__ uint32 ed[BUCKET_CAP];
    __shared__ uint32 ed2[BUCKET_CAP];
    __shared__ int bandcur[N_BANDS];
    __shared__ int ncnt[BUCKET_NODES];
    __shared__ int ncur[BUCKET_NODES];
    int b = blockIdx.x, t = threadIdx.x;
    int cnt = gcur[b];
    if (cnt > BUCKET_CAP) cnt = BUCKET_CAP;
    int obase = obase_arr[b];
    int n0 = b * BUCKET_NODES;

    if (t < N_BANDS) bandcur[t] = 0;
    if (t < BUCKET_NODES) ncnt[t] = 0;
    __syncthreads();

    const uint32* reg = packed + (size_t)b * BUCKET_CAP;
    for (int i = t; i < cnt; i += 256) {
        uint32 v = reg[i];
        ed[i] = v;
        atomicAdd(&bandcur[(v & 0x1FFFFu) >> 11], 1);
        atomicAdd(&ncnt[v >> 17], 1);
    }
    __syncthreads();

    if (t == 0) {
        int run = 0;
        for (int w = 0; w < N_BANDS; ++w) {
            int c = bandcur[w];
            bandcur[w] = run;
            run += c;
        }
    }
    int myc = (t < BUCKET_NODES) ? ncnt[t] : 0;
    if (t < BUCKET_NODES) ncur[t] = myc;
    __syncthreads();
    for (int off = 1; off < BUCKET_NODES; off <<= 1) {
        int v = 0;
        if (t < BUCKET_NODES && t >= off) v = ncur[t - off];
        __syncthreads();
        if (t < BUCKET_NODES) ncur[t] += v;
        __syncthreads();
    }
    if (t < BUCKET_NODES) {
        int excl = ncur[t] - myc;
        ncur[t] = excl;
        int gn = n0 + t;
        if (gn < N_NODES) row_ptr[gn] = obase + excl;
    }
    __syncthreads();

    for (int i = t; i < cnt; i += 256) {
        uint32 v = ed[i];
        int p = atomicAdd(&bandcur[(v & 0x1FFFFu) >> 11], 1);
        ed2[p] = v;
    }
    __syncthreads();

    for (int i = t; i < cnt; i += 256) {
        uint32 v = ed2[i];
        int slot = atomicAdd(&ncur[v >> 17], 1);
        col_src[obase + slot] = (int)(v & 0x1FFFFu);
    }
}

// ---------------------------------------------------------------------------
// Conversions
// ---------------------------------------------------------------------------
__global__ __launch_bounds__(256) void cvt_x(const float* __restrict__ x,
                                             u16* __restrict__ xb) {
    size_t base = ((size_t)blockIdx.x * 256 + threadIdx.x) * 8;
    if (base >= (size_t)M_PAD * DIM) return;
    int row = (int)(base >> 7);
    union { u16 u[8]; uint4 v; } o;
    if (row < N_NODES) {
        float4 v0 = *(const float4*)&x[base];
        float4 v1 = *(const float4*)&x[base + 4];
        o.u[0] = f2bf(v0.x); o.u[1] = f2bf(v0.y);
        o.u[2] = f2bf(v0.z); o.u[3] = f2bf(v0.w);
        o.u[4] = f2bf(v1.x); o.u[5] = f2bf(v1.y);
        o.u[6] = f2bf(v1.z); o.u[7] = f2bf(v1.w);
    } else {
        o.v = make_uint4(0, 0, 0, 0);
    }
    *(uint4*)&xb[base] = o.v;
}

// all 7 weight matrices -> WT[m][n][k] bf16 in one launch (m: 0=Wn,1..3=W1,4..6=W2)
__global__ void cvt_wt_all(const float* __restrict__ Wn, const float* __restrict__ W1,
                           const float* __restrict__ W2, u16* __restrict__ WT) {
    int m = blockIdx.x >> 7, n = blockIdx.x & 127, k = threadIdx.x;
    const float* src = (m == 0) ? Wn
                     : (m <= 3) ? W1 + (size_t)(m - 1) * DIM * DIM
                                : W2 + (size_t)(m - 4) * DIM * DIM;
    WT[((size_t)m * DIM + n) * DIM + k] = f2bf(src[(size_t)k * DIM + n]);
}

// ---------------------------------------------------------------------------
// Encoder GEMM: h = xb @ Wn + b (bf16 in/out, MFMA)
// ---------------------------------------------------------------------------
__global__ __launch_bounds__(256) void gemm_enc(const u16* __restrict__ A,
                                                const u16* __restrict__ WT,
                                                const float* __restrict__ bias,
                                                u16* __restrict__ out) {
    int t = threadIdx.x;
    int wid = t >> 6, lane = t & 63;
    int hw = lane >> 4, c = lane & 15;
    int rowA = blockIdx.x * 64 + wid * 16 + c;
    int kb = hw * 8;

    f32x4 acc[8];
#pragma unroll
    for (int i = 0; i < 8; ++i) acc[i] = (f32x4){0.f, 0.f, 0.f, 0.f};

#pragma unroll
    for (int ks = 0; ks < 4; ++ks) {
        int k0 = ks * 32 + kb;
        bf16x8 a = *(const bf16x8*)&A[(size_t)rowA * DIM + k0];
#pragma unroll
        for (int nf = 0; nf < 8; ++nf) {
            bf16x8 b = *(const bf16x8*)&WT[(size_t)(nf * 16 + c) * DIM + k0];
            acc[nf] = __builtin_amdgcn_mfma_f32_16x16x32_bf16(a, b, acc[nf], 0, 0, 0);
        }
    }
    int rbase = blockIdx.x * 64 + wid * 16 + hw * 4;
#pragma unroll
    for (int nf = 0; nf < 8; ++nf) {
        float bv = bias[nf * 16 + c];
#pragma unroll
        for (int r = 0; r < 4; ++r)
            out[(size_t)(rbase + r) * DIM + nf * 16 + c] = f2bf(acc[nf][r] + bv);
    }
}

// ---------------------------------------------------------------------------
// Fused aggregate + GEMM1 (+BN stats):
//   gather: quad q of each wave handles every 4th edge of the wave's row,
//   16 B/lane dwordx4 loads, f32 reg accum, shfl-reduce across quads,
//   bf16 pack into XOR-swizzled LDS tile; then MFMA from LDS.
// ---------------------------------------------------------------------------
__global__ __launch_bounds__(256) void fused_agg_gemm1(
    const u16* __restrict__ h, const int* __restrict__ row_ptr,
    const int* __restrict__ col_src, const u16* __restrict__ WT,
    const float* __restrict__ bias, u16* __restrict__ yout,
    float* __restrict__ bn_sum, float* __restrict__ bn_sumsq) {
    __shared__ u16 sA[64 * DIM];     // 16 KB, XOR-swizzled
    __shared__ float ls[4][DIM];
    __shared__ float lq[4][DIM];
    int t = threadIdx.x, wid = t >> 6, lane = t & 63;
    int q = lane >> 4, c = lane & 15;
    int row0 = blockIdx.x * 64;

    // ---- gather phase: wave wid owns rows wid*16 .. wid*16+15 ----
    for (int r = 0; r < 16; ++r) {
        int row = wid * 16 + r;
        int n = row0 + row;
        float acc[8];
#pragma unroll
        for (int j = 0; j < 8; ++j) acc[j] = 0.f;
        if (n < N_NODES) {
            if (q == 0) {  // self row (eps=0 -> 1.0*h)
                uint4 v = *(const uint4*)&h[(size_t)n * DIM + c * 8];
                acc[0] += lo_bf(v.x); acc[1] += hi_bf(v.x);
                acc[2] += lo_bf(v.y); acc[3] += hi_bf(v.y);
                acc[4] += lo_bf(v.z); acc[5] += hi_bf(v.z);
                acc[6] += lo_bf(v.w); acc[7] += hi_bf(v.w);
            }
            int beg = row_ptr[n], end = row_ptr[n + 1];
            int e = beg + q;
            for (; e + 4 < end; e += 8) {
                int i0 = col_src[e], i1 = col_src[e + 4];
                uint4 v0 = *(const uint4*)&h[(size_t)i0 * DIM + c * 8];
                uint4 v1 = *(const uint4*)&h[(size_t)i1 * DIM + c * 8];
                acc[0] += lo_bf(v0.x); acc[1] += hi_bf(v0.x);
                acc[2] += lo_bf(v0.y); acc[3] += hi_bf(v0.y);
                acc[4] += lo_bf(v0.z); acc[5] += hi_bf(v0.z);
                acc[6] += lo_bf(v0.w); acc[7] += hi_bf(v0.w);
                acc[0] += lo_bf(v1.x); acc[1] += hi_bf(v1.x);
                acc[2] += lo_bf(v1.y); acc[3] += hi_bf(v1.y);
                acc[4] += lo_bf(v1.z); acc[5] += hi_bf(v1.z);
                acc[6] += lo_bf(v1.w); acc[7] += hi_bf(v1.w);
            }
            if (e < end) {
                int i0 = col_src[e];
                uint4 v0 = *(const uint4*)&h[(size_t)i0 * DIM + c * 8];
                acc[0] += lo_bf(v0.x); acc[1] += hi_bf(v0.x);
                acc[2] += lo_bf(v0.y); acc[3] += hi_bf(v0.y);
                acc[4] += lo_bf(v0.z); acc[5] += hi_bf(v0.z);
                acc[6] += lo_bf(v0.w); acc[7] += hi_bf(v0.w);
            }
        }
        // reduce partial sums across quads
#pragma unroll
        for (int j = 0; j < 8; ++j) {
            acc[j] += __shfl_xor(acc[j], 16);
            acc[j] += __shfl_xor(acc[j], 32);
        }
        if (q == 0) {
            uint4 o;
            o.x = pack_bf2(acc[0], acc[1]);
            o.y = pack_bf2(acc[2], acc[3]);
            o.z = pack_bf2(acc[4], acc[5]);
            o.w = pack_bf2(acc[6], acc[7]);
            int boff = (row * 256 + c * 16) ^ ((row & 7) << 4);
            *(uint4*)((char*)sA + boff) = o;
        }
    }
    __syncthreads();

    // ---- MFMA phase ----
    int rowA = wid * 16 + c;
    f32x4 acc[8];
#pragma unroll
    for (int i = 0; i < 8; ++i) acc[i] = (f32x4){0.f, 0.f, 0.f, 0.f};
#pragma unroll
    for (int ks = 0; ks < 4; ++ks) {
        int k0 = ks * 32 + q * 8;
        int boff = (rowA * 256 + k0 * 2) ^ ((rowA & 7) << 4);
        bf16x8 a = *(const bf16x8*)((const char*)sA + boff);
#pragma unroll
        for (int nf = 0; nf < 8; ++nf) {
            bf16x8 b = *(const bf16x8*)&WT[(size_t)(nf * 16 + c) * DIM + k0];
            acc[nf] = __builtin_amdgcn_mfma_f32_16x16x32_bf16(a, b, acc[nf], 0, 0, 0);
        }
    }

    // ---- epilogue: bias, store y, BN stats ----
    int rbase = row0 + wid * 16 + q * 4;
    float s_[8], q_[8];
#pragma unroll
    for (int nf = 0; nf < 8; ++nf) {
        float bv = bias[nf * 16 + c];
        float ss = 0.f, qq = 0.f;
#pragma unroll
        for (int r = 0; r < 4; ++r) {
            float v = acc[nf][r] + bv;
            yout[(size_t)(rbase + r) * DIM + nf * 16 + c] = f2bf(v);
            float m = (rbase + r < N_NODES) ? v : 0.f;
            ss += m;
            qq += m * m;
        }
        s_[nf] = ss;
        q_[nf] = qq;
    }
#pragma unroll
    for (int nf = 0; nf < 8; ++nf) {
        s_[nf] += __shfl_xor(s_[nf], 16);
        s_[nf] += __shfl_xor(s_[nf], 32);
        q_[nf] += __shfl_xor(q_[nf], 16);
        q_[nf] += __shfl_xor(q_[nf], 32);
    }
    if (lane < 16) {
#pragma unroll
        for (int nf = 0; nf < 8; ++nf) {
            ls[wid][nf * 16 + c] = s_[nf];
            lq[wid][nf * 16 + c] = q_[nf];
        }
    }
    __syncthreads();
    if (t < DIM) {
        atomicAdd(&bn_sum[t], ls[0][t] + ls[1][t] + ls[2][t] + ls[3][t]);
        atomicAdd(&bn_sumsq[t], lq[0][t] + lq[1][t] + lq[2][t] + lq[3][t]);
    }
}

// ---------------------------------------------------------------------------
// GEMM2: h = relu( relu(BN(y)) @ W2 + b2 ), BN finalize inlined in prologue
// ---------------------------------------------------------------------------
__global__ __launch_bounds__(256) void gemm2_bn(const u16* __restrict__ A,
                                                const u16* __restrict__ WT,
                                                const float* __restrict__ bias,
                                                u16* __restrict__ out,
                                                const float* __restrict__ bn_sum,
                                                const float* __restrict__ bn_sumsq,
                                                const float* __restrict__ gamma,
                                                const float* __restrict__ beta) {
    __shared__ float s_scale[DIM];
    __shared__ float s_shift[DIM];
    int t = threadIdx.x;
    if (t < DIM) {
        const float invN = 1.0f / (float)N_NODES;
        float mean = bn_sum[t] * invN;
        float var = fmaxf(bn_sumsq[t] * invN - mean * mean, 0.f);
        float rs = rsqrtf(var + BN_EPS);
        float sc = gamma[t] * rs;
        s_scale[t] = sc;
        s_shift[t] = beta[t] - mean * sc;
    }
    __syncthreads();

    int wid = t >> 6, lane = t & 63;
    int hw = lane >> 4, c = lane & 15;
    int rowA = blockIdx.x * 64 + wid * 16 + c;
    int kb = hw * 8;

    f32x4 acc[8];
#pragma unroll
    for (int i = 0; i < 8; ++i) acc[i] = (f32x4){0.f, 0.f, 0.f, 0.f};

#pragma unroll
    for (int ks = 0; ks < 4; ++ks) {
        int k0 = ks * 32 + kb;
        bf16x8 a = *(const bf16x8*)&A[(size_t)rowA * DIM + k0];
        union { bf16x8 v; u16 u[8]; } ua;
        ua.v = a;
#pragma unroll
        for (int j = 0; j < 8; ++j) {
            float f = bf2f(ua.u[j]);
            f = fmaf(f, s_scale[k0 + j], s_shift[k0 + j]);
            f = fmaxf(f, 0.f);
            ua.u[j] = f2bf(f);
        }
        a = ua.v;
#pragma unroll
        for (int nf = 0; nf < 8; ++nf) {
            bf16x8 b = *(const bf16x8*)&WT[(size_t)(nf * 16 + c) * DIM + k0];
            acc[nf] = __builtin_amdgcn_mfma_f32_16x16x32_bf16(a, b, acc[nf], 0, 0, 0);
        }
    }
    int rbase = blockIdx.x * 64 + wid * 16 + hw * 4;
#pragma unroll
    for (int nf = 0; nf < 8; ++nf) {
        float bv = bias[nf * 16 + c];
#pragma unroll
        for (int r = 0; r < 4; ++r) {
            float v = fmaxf(acc[nf][r] + bv, 0.f);
            out[(size_t)(rbase + r) * DIM + nf * 16 + c] = f2bf(v);
        }
    }
}

// ---------------------------------------------------------------------------
// Global add pool (bf16 in, f32 out); batch sorted
// ---------------------------------------------------------------------------
__global__ __launch_bounds__(256) void pool_bf(const u16* __restrict__ h,
                                               const int* __restrict__ batch,
                                               float* __restrict__ out) {
    int wv = (blockIdx.x * 256 + threadIdx.x) >> 6;
    int lane = threadIdx.x & 63;
    int base = wv * 32;
    if (base >= N_NODES) return;
    int end = base + 32;
    if (end > N_NODES) end = N_NODES;
    const uint32* h32 = (const uint32*)h;
    float ax = 0.f, ay = 0.f;
    int curg = batch[base];
    for (int n = base; n < end; ++n) {
        int g = batch[n];
        if (g != curg) {
            atomicAdd(&out[curg * DIM + lane * 2], ax);
            atomicAdd(&out[curg * DIM + lane * 2 + 1], ay);
            ax = 0.f;
            ay = 0.f;
            curg = g;
        }
        uint32 v = h32[(size_t)n * 64 + lane];
        ax += lo_bf(v);
        ay += hi_bf(v);
    }
    atomicAdd(&out[curg * DIM + lane * 2], ax);
    atomicAdd(&out[curg * DIM + lane * 2 + 1], ay);
}

// ---------------------------------------------------------------------------
extern "C" void kernel_launch(void* const* d_in, const int* in_sizes, int n_in,
                              void* d_out, int out_size, void* d_ws, size_t ws_size,
                              hipStream_t stream) {
    const float* x     = (const float*)d_in[0];
    const int*   ei    = (const int*)d_in[1];
    const int*   batch = (const int*)d_in[2];
    const float* Wn    = (const float*)d_in[3];
    const float* bnode = (const float*)d_in[4];
    const float* W1    = (const float*)d_in[5];
    const float* b1    = (const float*)d_in[6];
    const float* gamma = (const float*)d_in[7];
    const float* beta  = (const float*)d_in[8];
    const float* W2    = (const float*)d_in[9];
    const float* b2    = (const float*)d_in[10];
    float* out = (float*)d_out;

    const int* e_src = ei;
    const int* e_dst = ei + N_EDGES;

    // workspace layout
    const size_t MD = (size_t)M_PAD * DIM;
    u16* xb = (u16*)d_ws;
    u16* h  = xb + MD;
    u16* y  = h + MD;
    u16* WT = y + MD;                       // 7 * 128 * 128
    int* row_ptr = (int*)(WT + 7 * DIM * DIM);
    int* col_src = row_ptr + N_NODES + 1;
    int* gcur    = col_src + N_EDGES;
    int* obase   = gcur + N_BUCKETS;
    float* bn_stats = (float*)(obase + N_BUCKETS);   // 3 layers * 2 * DIM
    // packed aliases y: used only during CSR build, before any GEMM writes y
    uint32* packed = (uint32*)y;            // 782*4864*4 B = 15.2 MB <= 25.6 MB

    const int GEMM_BLOCKS = M_PAD / 64;     // 1563
    const int POOL_BLOCKS = (((N_NODES + 31) / 32) * 64 + 255) / 256;
    const int CVT_BLOCKS = (int)(MD / 8 / 256);

    // ---- CSR build ----
    hipMemsetAsync(gcur, 0, N_BUCKETS * sizeof(int), stream);
    bin_by_dst<<<BIN_BLOCKS, 256, 0, stream>>>(e_src, e_dst, gcur, packed);
    scan_buckets<<<1, 256, 0, stream>>>(gcur, obase, row_ptr);
    build_buckets<<<N_BUCKETS, 256, 0, stream>>>(packed, gcur, obase, row_ptr, col_src);

    // ---- conversions ----
    cvt_x<<<CVT_BLOCKS, 256, 0, stream>>>(x, xb);
    cvt_wt_all<<<7 * DIM, DIM, 0, stream>>>(Wn, W1, W2, WT);
    hipMemsetAsync(bn_stats, 0, N_LAYERS * 2 * DIM * sizeof(float), stream);

    // ---- node encoder ----
    gemm_enc<<<GEMM_BLOCKS, 256, 0, stream>>>(xb, WT, bnode, h);

    // ---- GIN layers ----
    for (int i = 0; i < N_LAYERS; ++i) {
        float* bn_sum = bn_stats + (size_t)i * 2 * DIM;
        float* bn_sumsq = bn_sum + DIM;
        fused_agg_gemm1<<<GEMM_BLOCKS, 256, 0, stream>>>(
            h, row_ptr, col_src, WT + (size_t)(1 + i) * DIM * DIM, b1 + i * DIM,
            y, bn_sum, bn_sumsq);
        gemm2_bn<<<GEMM_BLOCKS, 256, 0, stream>>>(
            y, WT + (size_t)(4 + i) * DIM * DIM, b2 + i * DIM, h, bn_sum,
            bn_sumsq, gamma + i * DIM, beta + i * DIM);
    }

    // ---- global add pool ----
    hipMemsetAsync(out, 0, NUM_GRAPHS * DIM * sizeof(float), stream);
    pool_bf<<<POOL_BLOCKS, 256, 0, stream>>>(h, batch, out);
}

// Round 5
// 824.726 us; speedup vs baseline: 2.6457x; 1.0410x over previous
//
#include <hip/hip_runtime.h>

#define N_NODES 100000
#define M_PAD   100032   // padded to multiple of 64 rows
#define N_EDGES 3200000
#define DIM 128
#define N_LAYERS 3
#define NUM_GRAPHS 128
#define BN_EPS 1e-5f

// ---- binned CSR build parameters ----
#define DST_SHIFT 7
#define BUCKET_NODES 128
#define N_BUCKETS ((N_NODES + BUCKET_NODES - 1) / BUCKET_NODES)  // 782
#define BUCKET_CAP 4864
#define EDGES_PER_BLOCK 16384
#define BIN_BLOCKS ((N_EDGES + EDGES_PER_BLOCK - 1) / EDGES_PER_BLOCK)  // 196
#define N_BANDS 64   // used: (src>>11) in [0,49)

typedef unsigned int uint32;
typedef unsigned short u16;
typedef __attribute__((ext_vector_type(8))) short bf16x8;
typedef __attribute__((ext_vector_type(4))) float f32x4;

__device__ __forceinline__ float bf2f(u16 u) {
    union { uint32 i; float f; } c;
    c.i = ((uint32)u) << 16;
    return c.f;
}
__device__ __forceinline__ u16 f2bf(float f) {
    union { float f; uint32 i; } c;
    c.f = f;
    uint32 i = c.i;
    return (u16)((i + 0x7FFFu + ((i >> 16) & 1u)) >> 16);
}
__device__ __forceinline__ float lo_bf(uint32 v) {
    union { uint32 i; float f; } c;
    c.i = v << 16;
    return c.f;
}
__device__ __forceinline__ float hi_bf(uint32 v) {
    union { uint32 i; float f; } c;
    c.i = v & 0xFFFF0000u;
    return c.f;
}
__device__ __forceinline__ uint32 pack_bf2(float a, float b) {
    return ((uint32)f2bf(b) << 16) | (uint32)f2bf(a);
}
__device__ __forceinline__ void unpack_add8(float* acc, uint4 v) {
    acc[0] += lo_bf(v.x); acc[1] += hi_bf(v.x);
    acc[2] += lo_bf(v.y); acc[3] += hi_bf(v.y);
    acc[4] += lo_bf(v.z); acc[5] += hi_bf(v.z);
    acc[6] += lo_bf(v.w); acc[7] += hi_bf(v.w);
}

// ---------------------------------------------------------------------------
// Stage A: bin edges by dst bucket (2-pass, coalesced). packed = src|(dst&127)<<17
// ---------------------------------------------------------------------------
__global__ __launch_bounds__(256) void bin_by_dst(const int* __restrict__ src,
                                                  const int* __restrict__ dst,
                                                  int* __restrict__ gcur,
                                                  uint32* __restrict__ packed) {
    __shared__ int cnt[N_BUCKETS];
    __shared__ int cur[N_BUCKETS];
    int t = threadIdx.x;
    int e0 = blockIdx.x * EDGES_PER_BLOCK;
    for (int i = t; i < N_BUCKETS; i += 256) cnt[i] = 0;
    __syncthreads();

    for (int j = 0; j < EDGES_PER_BLOCK / 256; ++j) {
        int e = e0 + j * 256 + t;
        if (e < N_EDGES) atomicAdd(&cnt[dst[e] >> DST_SHIFT], 1);
    }
    __syncthreads();
    for (int i = t; i < N_BUCKETS; i += 256) {
        int c = cnt[i];
        cur[i] = c ? atomicAdd(&gcur[i], c) : 0;
    }
    __syncthreads();
    for (int j = 0; j < EDGES_PER_BLOCK / 256; ++j) {
        int e = e0 + j * 256 + t;
        if (e < N_EDGES) {
            int d = dst[e];
            int b = d >> DST_SHIFT;
            int pos = atomicAdd(&cur[b], 1);
            if (pos < BUCKET_CAP)
                packed[(size_t)b * BUCKET_CAP + pos] =
                    (uint32)src[e] | ((uint32)(d & (BUCKET_NODES - 1)) << 17);
        }
    }
}

// ---------------------------------------------------------------------------
__global__ void scan_buckets(const int* __restrict__ gcur, int* __restrict__ obase,
                             int* __restrict__ row_ptr) {
    __shared__ int s[N_BUCKETS];
    int t = threadIdx.x;
    for (int i = t; i < N_BUCKETS; i += 256) {
        int c = gcur[i];
        s[i] = (c > BUCKET_CAP) ? BUCKET_CAP : c;
    }
    __syncthreads();
    if (t == 0) {
        int run = 0;
        for (int i = 0; i < N_BUCKETS; ++i) {
            int c = s[i];
            s[i] = run;
            run += c;
        }
        row_ptr[N_NODES] = run;
    }
    __syncthreads();
    for (int i = t; i < N_BUCKETS; i += 256) obase[i] = s[i];
}

// ---------------------------------------------------------------------------
// Stage B: per bucket — row_ptr, band-sort by src>>11, place into col_src
// ---------------------------------------------------------------------------
__global__ __launch_bounds__(256) void build_buckets(const uint32* __restrict__ packed,
                                                     const int* __restrict__ gcur,
                                                     const int* __restrict__ obase_arr,
                                                     int* __restrict__ row_ptr,
                                                     int* __restrict__ col_src) {
    __shared__ uint32 ed[BUCKET_CAP];
    __shared__ uint32 ed2[BUCKET_CAP];
    __shared__ int bandcur[N_BANDS];
    __shared__ int ncnt[BUCKET_NODES];
    __shared__ int ncur[BUCKET_NODES];
    int b = blockIdx.x, t = threadIdx.x;
    int cnt = gcur[b];
    if (cnt > BUCKET_CAP) cnt = BUCKET_CAP;
    int obase = obase_arr[b];
    int n0 = b * BUCKET_NODES;

    if (t < N_BANDS) bandcur[t] = 0;
    if (t < BUCKET_NODES) ncnt[t] = 0;
    __syncthreads();

    const uint32* reg = packed + (size_t)b * BUCKET_CAP;
    for (int i = t; i < cnt; i += 256) {
        uint32 v = reg[i];
        ed[i] = v;
        atomicAdd(&bandcur[(v & 0x1FFFFu) >> 11], 1);
        atomicAdd(&ncnt[v >> 17], 1);
    }
    __syncthreads();

    if (t == 0) {
        int run = 0;
        for (int w = 0; w < N_BANDS; ++w) {
            int c = bandcur[w];
            bandcur[w] = run;
            run += c;
        }
    }
    int myc = (t < BUCKET_NODES) ? ncnt[t] : 0;
    if (t < BUCKET_NODES) ncur[t] = myc;
    __syncthreads();
    for (int off = 1; off < BUCKET_NODES; off <<= 1) {
        int v = 0;
        if (t < BUCKET_NODES && t >= off) v = ncur[t - off];
        __syncthreads();
        if (t < BUCKET_NODES) ncur[t] += v;
        __syncthreads();
    }
    if (t < BUCKET_NODES) {
        int excl = ncur[t] - myc;
        ncur[t] = excl;
        int gn = n0 + t;
        if (gn < N_NODES) row_ptr[gn] = obase + excl;
    }
    __syncthreads();

    for (int i = t; i < cnt; i += 256) {
        uint32 v = ed[i];
        int p = atomicAdd(&bandcur[(v & 0x1FFFFu) >> 11], 1);
        ed2[p] = v;
    }
    __syncthreads();

    for (int i = t; i < cnt; i += 256) {
        uint32 v = ed2[i];
        int slot = atomicAdd(&ncur[v >> 17], 1);
        col_src[obase + slot] = (int)(v & 0x1FFFFu);
    }
}

// ---------------------------------------------------------------------------
// Conversions
// ---------------------------------------------------------------------------
__global__ __launch_bounds__(256) void cvt_x(const float* __restrict__ x,
                                             u16* __restrict__ xb) {
    size_t base = ((size_t)blockIdx.x * 256 + threadIdx.x) * 8;
    if (base >= (size_t)M_PAD * DIM) return;
    int row = (int)(base >> 7);
    union { u16 u[8]; uint4 v; } o;
    if (row < N_NODES) {
        float4 v0 = *(const float4*)&x[base];
        float4 v1 = *(const float4*)&x[base + 4];
        o.u[0] = f2bf(v0.x); o.u[1] = f2bf(v0.y);
        o.u[2] = f2bf(v0.z); o.u[3] = f2bf(v0.w);
        o.u[4] = f2bf(v1.x); o.u[5] = f2bf(v1.y);
        o.u[6] = f2bf(v1.z); o.u[7] = f2bf(v1.w);
    } else {
        o.v = make_uint4(0, 0, 0, 0);
    }
    *(uint4*)&xb[base] = o.v;
}

// all 7 weight matrices -> WT[m][n][k] bf16 (m: 0=Wn, 1..3=W1, 4..6=W2)
__global__ void cvt_wt_all(const float* __restrict__ Wn, const float* __restrict__ W1,
                           const float* __restrict__ W2, u16* __restrict__ WT) {
    int m = blockIdx.x >> 7, n = blockIdx.x & 127, k = threadIdx.x;
    const float* src = (m == 0) ? Wn
                     : (m <= 3) ? W1 + (size_t)(m - 1) * DIM * DIM
                                : W2 + (size_t)(m - 4) * DIM * DIM;
    WT[((size_t)m * DIM + n) * DIM + k] = f2bf(src[(size_t)k * DIM + n]);
}

// ---------------------------------------------------------------------------
// Aggregation v2: one wave per node; quad q (16 lanes) loads one full 256 B
// row per edge via dwordx4 (16 B/lane); 2 edges unrolled -> 8 loads in
// flight/wave; f32 accum; cross-quad shfl reduce; bf16 store by quad 0.
// ---------------------------------------------------------------------------
__global__ __launch_bounds__(256) void aggregate_bf(const u16* __restrict__ h,
                                                    const int* __restrict__ row_ptr,
                                                    const int* __restrict__ col_src,
                                                    u16* __restrict__ agg) {
    int wv = (blockIdx.x * 256 + threadIdx.x) >> 6;
    int lane = threadIdx.x & 63;
    int q = lane >> 4, c = lane & 15;
    if (wv >= N_NODES) return;
    int beg = row_ptr[wv], end = row_ptr[wv + 1];
    const uint4* h4 = (const uint4*)h;   // one row = 16 uint4

    float acc[8];
#pragma unroll
    for (int j = 0; j < 8; ++j) acc[j] = 0.f;

    if (q == 0) {  // self contribution (1+eps)*h, eps=0
        uint4 v = h4[(size_t)wv * 16 + c];
        unpack_add8(acc, v);
    }
    int e = beg + q;
    for (; e + 4 < end; e += 8) {
        int i0 = col_src[e];
        int i1 = col_src[e + 4];
        uint4 v0 = h4[(size_t)i0 * 16 + c];
        uint4 v1 = h4[(size_t)i1 * 16 + c];
        unpack_add8(acc, v0);
        unpack_add8(acc, v1);
    }
    if (e < end) {
        uint4 v0 = h4[(size_t)col_src[e] * 16 + c];
        unpack_add8(acc, v0);
    }
#pragma unroll
    for (int j = 0; j < 8; ++j) {
        acc[j] += __shfl_xor(acc[j], 16);
        acc[j] += __shfl_xor(acc[j], 32);
    }
    if (q == 0) {
        uint4 o;
        o.x = pack_bf2(acc[0], acc[1]);
        o.y = pack_bf2(acc[2], acc[3]);
        o.z = pack_bf2(acc[4], acc[5]);
        o.w = pack_bf2(acc[6], acc[7]);
        *(uint4*)&agg[(size_t)wv * DIM + c * 8] = o;
    }
}

// ---------------------------------------------------------------------------
// Encoder GEMM: h = xb @ Wn + b (bf16 in/out, MFMA)
// ---------------------------------------------------------------------------
__global__ __launch_bounds__(256) void gemm_enc(const u16* __restrict__ A,
                                                const u16* __restrict__ WT,
                                                const float* __restrict__ bias,
                                                u16* __restrict__ out) {
    int t = threadIdx.x;
    int wid = t >> 6, lane = t & 63;
    int hw = lane >> 4, c = lane & 15;
    int rowA = blockIdx.x * 64 + wid * 16 + c;
    int kb = hw * 8;

    f32x4 acc[8];
#pragma unroll
    for (int i = 0; i < 8; ++i) acc[i] = (f32x4){0.f, 0.f, 0.f, 0.f};

#pragma unroll
    for (int ks = 0; ks < 4; ++ks) {
        int k0 = ks * 32 + kb;
        bf16x8 a = *(const bf16x8*)&A[(size_t)rowA * DIM + k0];
#pragma unroll
        for (int nf = 0; nf < 8; ++nf) {
            bf16x8 b = *(const bf16x8*)&WT[(size_t)(nf * 16 + c) * DIM + k0];
            acc[nf] = __builtin_amdgcn_mfma_f32_16x16x32_bf16(a, b, acc[nf], 0, 0, 0);
        }
    }
    int rbase = blockIdx.x * 64 + wid * 16 + hw * 4;
#pragma unroll
    for (int nf = 0; nf < 8; ++nf) {
        float bv = bias[nf * 16 + c];
#pragma unroll
        for (int r = 0; r < 4; ++r)
            out[(size_t)(rbase + r) * DIM + nf * 16 + c] = f2bf(acc[nf][r] + bv);
    }
}

// ---------------------------------------------------------------------------
// GEMM1 (+BN stats): y = agg @ W1 + b1; per-column sum / sumsq accumulated
// ---------------------------------------------------------------------------
__global__ __launch_bounds__(256) void gemm1_stats(const u16* __restrict__ A,
                                                   const u16* __restrict__ WT,
                                                   const float* __restrict__ bias,
                                                   u16* __restrict__ yout,
                                                   float* __restrict__ bn_sum,
                                                   float* __restrict__ bn_sumsq) {
    __shared__ float ls[4][DIM];
    __shared__ float lq[4][DIM];
    int t = threadIdx.x;
    int wid = t >> 6, lane = t & 63;
    int hw = lane >> 4, c = lane & 15;
    int rowA = blockIdx.x * 64 + wid * 16 + c;
    int kb = hw * 8;

    f32x4 acc[8];
#pragma unroll
    for (int i = 0; i < 8; ++i) acc[i] = (f32x4){0.f, 0.f, 0.f, 0.f};

#pragma unroll
    for (int ks = 0; ks < 4; ++ks) {
        int k0 = ks * 32 + kb;
        bf16x8 a = *(const bf16x8*)&A[(size_t)rowA * DIM + k0];
#pragma unroll
        for (int nf = 0; nf < 8; ++nf) {
            bf16x8 b = *(const bf16x8*)&WT[(size_t)(nf * 16 + c) * DIM + k0];
            acc[nf] = __builtin_amdgcn_mfma_f32_16x16x32_bf16(a, b, acc[nf], 0, 0, 0);
        }
    }

    int rbase = blockIdx.x * 64 + wid * 16 + hw * 4;
    float s_[8], q_[8];
#pragma unroll
    for (int nf = 0; nf < 8; ++nf) {
        float bv = bias[nf * 16 + c];
        float ss = 0.f, qq = 0.f;
#pragma unroll
        for (int r = 0; r < 4; ++r) {
            float v = acc[nf][r] + bv;
            yout[(size_t)(rbase + r) * DIM + nf * 16 + c] = f2bf(v);
            float m = (rbase + r < N_NODES) ? v : 0.f;
            ss += m;
            qq += m * m;
        }
        s_[nf] = ss;
        q_[nf] = qq;
    }
#pragma unroll
    for (int nf = 0; nf < 8; ++nf) {
        s_[nf] += __shfl_xor(s_[nf], 16);
        s_[nf] += __shfl_xor(s_[nf], 32);
        q_[nf] += __shfl_xor(q_[nf], 16);
        q_[nf] += __shfl_xor(q_[nf], 32);
    }
    if (lane < 16) {
#pragma unroll
        for (int nf = 0; nf < 8; ++nf) {
            ls[wid][nf * 16 + c] = s_[nf];
            lq[wid][nf * 16 + c] = q_[nf];
        }
    }
    __syncthreads();
    if (t < DIM) {
        atomicAdd(&bn_sum[t], ls[0][t] + ls[1][t] + ls[2][t] + ls[3][t]);
        atomicAdd(&bn_sumsq[t], lq[0][t] + lq[1][t] + lq[2][t] + lq[3][t]);
    }
}

// ---------------------------------------------------------------------------
// GEMM2: h = relu( relu(BN(y)) @ W2 + b2 ), BN finalize inlined in prologue
// ---------------------------------------------------------------------------
__global__ __launch_bounds__(256) void gemm2_bn(const u16* __restrict__ A,
                                                const u16* __restrict__ WT,
                                                const float* __restrict__ bias,
                                                u16* __restrict__ out,
                                                const float* __restrict__ bn_sum,
                                                const float* __restrict__ bn_sumsq,
                                                const float* __restrict__ gamma,
                                                const float* __restrict__ beta) {
    __shared__ float s_scale[DIM];
    __shared__ float s_shift[DIM];
    int t = threadIdx.x;
    if (t < DIM) {
        const float invN = 1.0f / (float)N_NODES;
        float mean = bn_sum[t] * invN;
        float var = fmaxf(bn_sumsq[t] * invN - mean * mean, 0.f);
        float rs = rsqrtf(var + BN_EPS);
        float sc = gamma[t] * rs;
        s_scale[t] = sc;
        s_shift[t] = beta[t] - mean * sc;
    }
    __syncthreads();

    int wid = t >> 6, lane = t & 63;
    int hw = lane >> 4, c = lane & 15;
    int rowA = blockIdx.x * 64 + wid * 16 + c;
    int kb = hw * 8;

    f32x4 acc[8];
#pragma unroll
    for (int i = 0; i < 8; ++i) acc[i] = (f32x4){0.f, 0.f, 0.f, 0.f};

#pragma unroll
    for (int ks = 0; ks < 4; ++ks) {
        int k0 = ks * 32 + kb;
        bf16x8 a = *(const bf16x8*)&A[(size_t)rowA * DIM + k0];
        union { bf16x8 v; u16 u[8]; } ua;
        ua.v = a;
#pragma unroll
        for (int j = 0; j < 8; ++j) {
            float f = bf2f(ua.u[j]);
            f = fmaf(f, s_scale[k0 + j], s_shift[k0 + j]);
            f = fmaxf(f, 0.f);
            ua.u[j] = f2bf(f);
        }
        a = ua.v;
#pragma unroll
        for (int nf = 0; nf < 8; ++nf) {
            bf16x8 b = *(const bf16x8*)&WT[(size_t)(nf * 16 + c) * DIM + k0];
            acc[nf] = __builtin_amdgcn_mfma_f32_16x16x32_bf16(a, b, acc[nf], 0, 0, 0);
        }
    }
    int rbase = blockIdx.x * 64 + wid * 16 + hw * 4;
#pragma unroll
    for (int nf = 0; nf < 8; ++nf) {
        float bv = bias[nf * 16 + c];
#pragma unroll
        for (int r = 0; r < 4; ++r) {
            float v = fmaxf(acc[nf][r] + bv, 0.f);
            out[(size_t)(rbase + r) * DIM + nf * 16 + c] = f2bf(v);
        }
    }
}

// ---------------------------------------------------------------------------
// Global add pool (bf16 in, f32 out); batch sorted
// ---------------------------------------------------------------------------
__global__ __launch_bounds__(256) void pool_bf(const u16* __restrict__ h,
                                               const int* __restrict__ batch,
                                               float* __restrict__ out) {
    int wv = (blockIdx.x * 256 + threadIdx.x) >> 6;
    int lane = threadIdx.x & 63;
    int base = wv * 32;
    if (base >= N_NODES) return;
    int end = base + 32;
    if (end > N_NODES) end = N_NODES;
    const uint32* h32 = (const uint32*)h;
    float ax = 0.f, ay = 0.f;
    int curg = batch[base];
    for (int n = base; n < end; ++n) {
        int g = batch[n];
        if (g != curg) {
            atomicAdd(&out[curg * DIM + lane * 2], ax);
            atomicAdd(&out[curg * DIM + lane * 2 + 1], ay);
            ax = 0.f;
            ay = 0.f;
            curg = g;
        }
        uint32 v = h32[(size_t)n * 64 + lane];
        ax += lo_bf(v);
        ay += hi_bf(v);
    }
    atomicAdd(&out[curg * DIM + lane * 2], ax);
    atomicAdd(&out[curg * DIM + lane * 2 + 1], ay);
}

// ---------------------------------------------------------------------------
extern "C" void kernel_launch(void* const* d_in, const int* in_sizes, int n_in,
                              void* d_out, int out_size, void* d_ws, size_t ws_size,
                              hipStream_t stream) {
    const float* x     = (const float*)d_in[0];
    const int*   ei    = (const int*)d_in[1];
    const int*   batch = (const int*)d_in[2];
    const float* Wn    = (const float*)d_in[3];
    const float* bnode = (const float*)d_in[4];
    const float* W1    = (const float*)d_in[5];
    const float* b1    = (const float*)d_in[6];
    const float* gamma = (const float*)d_in[7];
    const float* beta  = (const float*)d_in[8];
    const float* W2    = (const float*)d_in[9];
    const float* b2    = (const float*)d_in[10];
    float* out = (float*)d_out;

    const int* e_src = ei;
    const int* e_dst = ei + N_EDGES;

    // workspace layout
    const size_t MD = (size_t)M_PAD * DIM;
    u16* xb  = (u16*)d_ws;
    u16* h   = xb + MD;
    u16* agg = h + MD;
    u16* y   = agg + MD;
    u16* WT  = y + MD;                      // 7 * 128 * 128
    int* row_ptr = (int*)(WT + 7 * DIM * DIM);
    int* col_src = row_ptr + N_NODES + 1;
    int* gcur    = col_src + N_EDGES;
    int* obase   = gcur + N_BUCKETS;
    float* bn_stats = (float*)(obase + N_BUCKETS);   // 3 layers * 2 * DIM
    // packed aliases y: used only during CSR build, before any GEMM writes y
    uint32* packed = (uint32*)y;            // 782*4864*4 B = 15.2 MB <= 25.6 MB

    const int GEMM_BLOCKS = M_PAD / 64;     // 1563
    const int AGG_BLOCKS = (N_NODES * 64 + 255) / 256;   // 25000
    const int POOL_BLOCKS = (((N_NODES + 31) / 32) * 64 + 255) / 256;
    const int CVT_BLOCKS = (int)(MD / 8 / 256);

    // ---- CSR build ----
    hipMemsetAsync(gcur, 0, N_BUCKETS * sizeof(int), stream);
    bin_by_dst<<<BIN_BLOCKS, 256, 0, stream>>>(e_src, e_dst, gcur, packed);
    scan_buckets<<<1, 256, 0, stream>>>(gcur, obase, row_ptr);
    build_buckets<<<N_BUCKETS, 256, 0, stream>>>(packed, gcur, obase, row_ptr, col_src);

    // ---- conversions ----
    cvt_x<<<CVT_BLOCKS, 256, 0, stream>>>(x, xb);
    cvt_wt_all<<<7 * DIM, DIM, 0, stream>>>(Wn, W1, W2, WT);
    hipMemsetAsync(bn_stats, 0, N_LAYERS * 2 * DIM * sizeof(float), stream);
    // zero agg pad rows (gemm1 reads them; stats mask them but keep them finite)
    hipMemsetAsync(agg + (size_t)N_NODES * DIM, 0,
                   (M_PAD - N_NODES) * DIM * sizeof(u16), stream);

    // ---- node encoder ----
    gemm_enc<<<GEMM_BLOCKS, 256, 0, stream>>>(xb, WT, bnode, h);

    // ---- GIN layers ----
    for (int i = 0; i < N_LAYERS; ++i) {
        float* bn_sum = bn_stats + (size_t)i * 2 * DIM;
        float* bn_sumsq = bn_sum + DIM;
        aggregate_bf<<<AGG_BLOCKS, 256, 0, stream>>>(h, row_ptr, col_src, agg);
        gemm1_stats<<<GEMM_BLOCKS, 256, 0, stream>>>(
            agg, WT + (size_t)(1 + i) * DIM * DIM, b1 + i * DIM, y, bn_sum, bn_sumsq);
        gemm2_bn<<<GEMM_BLOCKS, 256, 0, stream>>>(
            y, WT + (size_t)(4 + i) * DIM * DIM, b2 + i * DIM, h, bn_sum,
            bn_sumsq, gamma + i * DIM, beta + i * DIM);
    }

    // ---- global add pool ----
    hipMemsetAsync(out, 0, NUM_GRAPHS * DIM * sizeof(float), stream);
    pool_bf<<<POOL_BLOCKS, 256, 0, stream>>>(h, batch, out);
}

// Round 6
// 615.023 us; speedup vs baseline: 3.5478x; 1.3410x over previous
//
#include <hip/hip_runtime.h>

#define N_NODES 100000
#define M_PAD   100096   // multiple of 128 rows
#define N_EDGES 3200000
#define DIM 128
#define N_LAYERS 3
#define NUM_GRAPHS 128
#define BN_EPS 1e-5f

// ---- binned CSR build parameters ----
#define DST_SHIFT 7
#define BUCKET_NODES 128
#define N_BUCKETS ((N_NODES + BUCKET_NODES - 1) / BUCKET_NODES)  // 782
#define BUCKET_CAP 4864
#define EDGES_PER_BLOCK 16384
#define BIN_BLOCKS ((N_EDGES + EDGES_PER_BLOCK - 1) / EDGES_PER_BLOCK)  // 196
#define N_BANDS 64   // used: (src>>11) in [0,49)

typedef unsigned int uint32;
typedef unsigned short u16;
typedef __attribute__((ext_vector_type(8))) short bf16x8;
typedef __attribute__((ext_vector_type(4))) float f32x4;

__device__ __forceinline__ float bf2f(u16 u) {
    union { uint32 i; float f; } c;
    c.i = ((uint32)u) << 16;
    return c.f;
}
__device__ __forceinline__ u16 f2bf(float f) {
    union { float f; uint32 i; } c;
    c.f = f;
    uint32 i = c.i;
    return (u16)((i + 0x7FFFu + ((i >> 16) & 1u)) >> 16);
}
__device__ __forceinline__ float lo_bf(uint32 v) {
    union { uint32 i; float f; } c;
    c.i = v << 16;
    return c.f;
}
__device__ __forceinline__ float hi_bf(uint32 v) {
    union { uint32 i; float f; } c;
    c.i = v & 0xFFFF0000u;
    return c.f;
}
__device__ __forceinline__ uint32 pack_bf2(float a, float b) {
    return ((uint32)f2bf(b) << 16) | (uint32)f2bf(a);
}
__device__ __forceinline__ void unpack_add8(float* acc, uint4 v) {
    acc[0] += lo_bf(v.x); acc[1] += hi_bf(v.x);
    acc[2] += lo_bf(v.y); acc[3] += hi_bf(v.y);
    acc[4] += lo_bf(v.z); acc[5] += hi_bf(v.z);
    acc[6] += lo_bf(v.w); acc[7] += hi_bf(v.w);
}

// ---------------------------------------------------------------------------
// zero_misc: one launch replaces 4 memsets
// ---------------------------------------------------------------------------
__global__ __launch_bounds__(256) void zero_misc(int* __restrict__ gcur,
                                                 float* __restrict__ bn_stats,
                                                 float* __restrict__ outp,
                                                 uint32* __restrict__ aggpad32) {
    int i = blockIdx.x * 256 + threadIdx.x;
    if (i < N_BUCKETS) gcur[i] = 0;
    if (i < N_LAYERS * 2 * DIM) bn_stats[i] = 0.f;
    if (i < NUM_GRAPHS * DIM) outp[i] = 0.f;
    if (i < (M_PAD - N_NODES) * DIM / 2) aggpad32[i] = 0;
}

// ---------------------------------------------------------------------------
// Stage A: bin edges by dst bucket (2-pass, coalesced). packed = src|(dst&127)<<17
// ---------------------------------------------------------------------------
__global__ __launch_bounds__(256) void bin_by_dst(const int* __restrict__ src,
                                                  const int* __restrict__ dst,
                                                  int* __restrict__ gcur,
                                                  uint32* __restrict__ packed) {
    __shared__ int cnt[N_BUCKETS];
    __shared__ int cur[N_BUCKETS];
    int t = threadIdx.x;
    int e0 = blockIdx.x * EDGES_PER_BLOCK;
    for (int i = t; i < N_BUCKETS; i += 256) cnt[i] = 0;
    __syncthreads();

    for (int j = 0; j < EDGES_PER_BLOCK / 256; ++j) {
        int e = e0 + j * 256 + t;
        if (e < N_EDGES) atomicAdd(&cnt[dst[e] >> DST_SHIFT], 1);
    }
    __syncthreads();
    for (int i = t; i < N_BUCKETS; i += 256) {
        int c = cnt[i];
        cur[i] = c ? atomicAdd(&gcur[i], c) : 0;
    }
    __syncthreads();
    for (int j = 0; j < EDGES_PER_BLOCK / 256; ++j) {
        int e = e0 + j * 256 + t;
        if (e < N_EDGES) {
            int d = dst[e];
            int b = d >> DST_SHIFT;
            int pos = atomicAdd(&cur[b], 1);
            if (pos < BUCKET_CAP)
                packed[(size_t)b * BUCKET_CAP + pos] =
                    (uint32)src[e] | ((uint32)(d & (BUCKET_NODES - 1)) << 17);
        }
    }
}

// ---------------------------------------------------------------------------
__global__ void scan_buckets(const int* __restrict__ gcur, int* __restrict__ obase,
                             int* __restrict__ row_ptr) {
    __shared__ int s[N_BUCKETS];
    int t = threadIdx.x;
    for (int i = t; i < N_BUCKETS; i += 256) {
        int c = gcur[i];
        s[i] = (c > BUCKET_CAP) ? BUCKET_CAP : c;
    }
    __syncthreads();
    if (t == 0) {
        int run = 0;
        for (int i = 0; i < N_BUCKETS; ++i) {
            int c = s[i];
            s[i] = run;
            run += c;
        }
        row_ptr[N_NODES] = run;
    }
    __syncthreads();
    for (int i = t; i < N_BUCKETS; i += 256) obase[i] = s[i];
}

// ---------------------------------------------------------------------------
// Stage B: per bucket — row_ptr, band-sort by src>>11, place into col_src
// ---------------------------------------------------------------------------
__global__ __launch_bounds__(256) void build_buckets(const uint32* __restrict__ packed,
                                                     const int* __restrict__ gcur,
                                                     const int* __restrict__ obase_arr,
                                                     int* __restrict__ row_ptr,
                                                     int* __restrict__ col_src) {
    __shared__ uint32 ed[BUCKET_CAP];
    __shared__ uint32 ed2[BUCKET_CAP];
    __shared__ int bandcur[N_BANDS];
    __shared__ int ncnt[BUCKET_NODES];
    __shared__ int ncur[BUCKET_NODES];
    int b = blockIdx.x, t = threadIdx.x;
    int cnt = gcur[b];
    if (cnt > BUCKET_CAP) cnt = BUCKET_CAP;
    int obase = obase_arr[b];
    int n0 = b * BUCKET_NODES;

    if (t < N_BANDS) bandcur[t] = 0;
    if (t < BUCKET_NODES) ncnt[t] = 0;
    __syncthreads();

    const uint32* reg = packed + (size_t)b * BUCKET_CAP;
    for (int i = t; i < cnt; i += 256) {
        uint32 v = reg[i];
        ed[i] = v;
        atomicAdd(&bandcur[(v & 0x1FFFFu) >> 11], 1);
        atomicAdd(&ncnt[v >> 17], 1);
    }
    __syncthreads();

    if (t == 0) {
        int run = 0;
        for (int w = 0; w < N_BANDS; ++w) {
            int c = bandcur[w];
            bandcur[w] = run;
            run += c;
        }
    }
    int myc = (t < BUCKET_NODES) ? ncnt[t] : 0;
    if (t < BUCKET_NODES) ncur[t] = myc;
    __syncthreads();
    for (int off = 1; off < BUCKET_NODES; off <<= 1) {
        int v = 0;
        if (t < BUCKET_NODES && t >= off) v = ncur[t - off];
        __syncthreads();
        if (t < BUCKET_NODES) ncur[t] += v;
        __syncthreads();
    }
    if (t < BUCKET_NODES) {
        int excl = ncur[t] - myc;
        ncur[t] = excl;
        int gn = n0 + t;
        if (gn < N_NODES) row_ptr[gn] = obase + excl;
    }
    __syncthreads();

    for (int i = t; i < cnt; i += 256) {
        uint32 v = ed[i];
        int p = atomicAdd(&bandcur[(v & 0x1FFFFu) >> 11], 1);
        ed2[p] = v;
    }
    __syncthreads();

    for (int i = t; i < cnt; i += 256) {
        uint32 v = ed2[i];
        int slot = atomicAdd(&ncur[v >> 17], 1);
        col_src[obase + slot] = (int)(v & 0x1FFFFu);
    }
}

// ---------------------------------------------------------------------------
// All 7 weight matrices -> WT bf16, transposed (n-major) AND pre-swizzled:
// element (n,k) stored at byte (n*256 + k*2) ^ ((n&7)<<4) within its matrix.
// A linear copy into LDS then lands swizzled; ds_read_b128 of row n at col k0
// applies the same XOR -> even 8-way bank-group spread (2 lanes/group).
// ---------------------------------------------------------------------------
__global__ void cvt_wt_all(const float* __restrict__ Wn, const float* __restrict__ W1,
                           const float* __restrict__ W2, u16* __restrict__ WT) {
    int m = blockIdx.x >> 7, n = blockIdx.x & 127, k = threadIdx.x;
    const float* src = (m == 0) ? Wn
                     : (m <= 3) ? W1 + (size_t)(m - 1) * DIM * DIM
                                : W2 + (size_t)(m - 4) * DIM * DIM;
    int L = n * 256 + k * 2;
    int Ls = L ^ ((n & 7) << 4);
    *(u16*)((char*)WT + (size_t)m * 32768 + Ls) = f2bf(src[(size_t)k * DIM + n]);
}

// ---------------------------------------------------------------------------
// Aggregation: one wave per node; quad q loads one 256 B row per edge via
// dwordx4 (16 B/lane); 4 edges in flight per quad; f32 accum; shfl reduce.
// ---------------------------------------------------------------------------
__global__ __launch_bounds__(256) void aggregate_bf(const u16* __restrict__ h,
                                                    const int* __restrict__ row_ptr,
                                                    const int* __restrict__ col_src,
                                                    u16* __restrict__ agg) {
    int wv = (blockIdx.x * 256 + threadIdx.x) >> 6;
    int lane = threadIdx.x & 63;
    int q = lane >> 4, c = lane & 15;
    if (wv >= N_NODES) return;
    int beg = row_ptr[wv], end = row_ptr[wv + 1];
    const uint4* h4 = (const uint4*)h;   // one row = 16 uint4

    float acc[8];
#pragma unroll
    for (int j = 0; j < 8; ++j) acc[j] = 0.f;

    if (q == 0) {  // self contribution (1+eps)*h, eps=0
        uint4 v = h4[(size_t)wv * 16 + c];
        unpack_add8(acc, v);
    }
    int e = beg + q;
    for (; e + 12 < end; e += 16) {
        int i0 = col_src[e];
        int i1 = col_src[e + 4];
        int i2 = col_src[e + 8];
        int i3 = col_src[e + 12];
        uint4 v0 = h4[(size_t)i0 * 16 + c];
        uint4 v1 = h4[(size_t)i1 * 16 + c];
        uint4 v2 = h4[(size_t)i2 * 16 + c];
        uint4 v3 = h4[(size_t)i3 * 16 + c];
        unpack_add8(acc, v0);
        unpack_add8(acc, v1);
        unpack_add8(acc, v2);
        unpack_add8(acc, v3);
    }
    for (; e < end; e += 4) {
        uint4 v0 = h4[(size_t)col_src[e] * 16 + c];
        unpack_add8(acc, v0);
    }
#pragma unroll
    for (int j = 0; j < 8; ++j) {
        acc[j] += __shfl_xor(acc[j], 16);
        acc[j] += __shfl_xor(acc[j], 32);
    }
    if (q == 0) {
        uint4 o;
        o.x = pack_bf2(acc[0], acc[1]);
        o.y = pack_bf2(acc[2], acc[3]);
        o.z = pack_bf2(acc[4], acc[5]);
        o.w = pack_bf2(acc[6], acc[7]);
        *(uint4*)&agg[(size_t)wv * DIM + c * 8] = o;
    }
}

// ---------------------------------------------------------------------------
// GEMM v2: 128 rows x 128 cols per block (256 thr = 4 waves, 32 rows/wave).
// B (32 KB, pre-swizzled) staged in LDS once; ds_read_b128 conflict-even.
// MODE 0: A = f32 x (encoder, fused cvt)    -> out = A@W + b
// MODE 1: A = bf16 agg, BN stats epilogue   -> y = A@W1 + b1, sum/sumsq
// MODE 2: A = bf16 y, BN+ReLU pre, ReLU post-> h = relu(relu(BN(y))@W2 + b2)
// ---------------------------------------------------------------------------
template <int MODE>
__global__ __launch_bounds__(256) void gemm_v2(const void* __restrict__ Av,
                                               const u16* __restrict__ WTs,
                                               const float* __restrict__ bias,
                                               u16* __restrict__ outp,
                                               float* __restrict__ bn_sum,
                                               float* __restrict__ bn_sumsq,
                                               const float* __restrict__ gamma,
                                               const float* __restrict__ beta) {
    __shared__ u16 sB[DIM * DIM];     // 32 KB swizzled
    __shared__ float sc_[DIM];
    __shared__ float sh_[DIM];
    __shared__ float ls[4][DIM];
    __shared__ float lq[4][DIM];

    int t = threadIdx.x;
    // stage B: linear 32 KB copy (swizzle already baked into global layout)
    {
        const uint4* Wg = (const uint4*)WTs;
        uint4* sB4 = (uint4*)sB;
#pragma unroll
        for (int i = 0; i < 8; ++i) sB4[i * 256 + t] = Wg[i * 256 + t];
    }
    if (MODE == 2 && t < DIM) {
        const float invN = 1.0f / (float)N_NODES;
        float mean = bn_sum[t] * invN;
        float var = fmaxf(bn_sumsq[t] * invN - mean * mean, 0.f);
        float rs = rsqrtf(var + BN_EPS);
        float sc = gamma[t] * rs;
        sc_[t] = sc;
        sh_[t] = beta[t] - mean * sc;
    }
    __syncthreads();

    int wid = t >> 6, lane = t & 63;
    int hw = lane >> 4, c = lane & 15;
    int row0 = blockIdx.x * 128 + wid * 32;

    // ---- A fragments (2 row-frags x 4 k-steps) ----
    bf16x8 a[2][4];
#pragma unroll
    for (int rf = 0; rf < 2; ++rf) {
        int row = row0 + rf * 16 + c;
#pragma unroll
        for (int ks = 0; ks < 4; ++ks) {
            int k0 = ks * 32 + hw * 8;
            if (MODE == 0) {
                const float* xf = (const float*)Av;
                float4 v0 = make_float4(0.f, 0.f, 0.f, 0.f), v1 = v0;
                if (row < N_NODES) {
                    v0 = *(const float4*)&xf[(size_t)row * DIM + k0];
                    v1 = *(const float4*)&xf[(size_t)row * DIM + k0 + 4];
                }
                union { bf16x8 v; u16 u[8]; } ua;
                ua.u[0] = f2bf(v0.x); ua.u[1] = f2bf(v0.y);
                ua.u[2] = f2bf(v0.z); ua.u[3] = f2bf(v0.w);
                ua.u[4] = f2bf(v1.x); ua.u[5] = f2bf(v1.y);
                ua.u[6] = f2bf(v1.z); ua.u[7] = f2bf(v1.w);
                a[rf][ks] = ua.v;
            } else {
                const u16* Ab = (const u16*)Av;
                bf16x8 av = *(const bf16x8*)&Ab[(size_t)row * DIM + k0];
                if (MODE == 2) {
                    union { bf16x8 v; u16 u[8]; } ua;
                    ua.v = av;
#pragma unroll
                    for (int j = 0; j < 8; ++j) {
                        float f = bf2f(ua.u[j]);
                        f = fmaxf(fmaf(f, sc_[k0 + j], sh_[k0 + j]), 0.f);
                        ua.u[j] = f2bf(f);
                    }
                    av = ua.v;
                }
                a[rf][ks] = av;
            }
        }
    }

    // ---- MFMA from LDS B ----
    f32x4 acc[2][8];
#pragma unroll
    for (int rf = 0; rf < 2; ++rf)
#pragma unroll
        for (int nf = 0; nf < 8; ++nf) acc[rf][nf] = (f32x4){0.f, 0.f, 0.f, 0.f};

    int swz = (c & 7) << 4;
#pragma unroll
    for (int ks = 0; ks < 4; ++ks) {
#pragma unroll
        for (int nf = 0; nf < 8; ++nf) {
            int L = (nf * 4096 + c * 256 + ks * 64 + hw * 16) ^ swz;
            bf16x8 b = *(const bf16x8*)((const char*)sB + L);
            acc[0][nf] = __builtin_amdgcn_mfma_f32_16x16x32_bf16(a[0][ks], b, acc[0][nf], 0, 0, 0);
            acc[1][nf] = __builtin_amdgcn_mfma_f32_16x16x32_bf16(a[1][ks], b, acc[1][nf], 0, 0, 0);
        }
    }

    // ---- epilogue ----
    float s_[8], q_[8];
#pragma unroll
    for (int nf = 0; nf < 8; ++nf) { s_[nf] = 0.f; q_[nf] = 0.f; }

#pragma unroll
    for (int rf = 0; rf < 2; ++rf) {
        int rbase = row0 + rf * 16 + hw * 4;
#pragma unroll
        for (int nf = 0; nf < 8; ++nf) {
            float bv = bias[nf * 16 + c];
#pragma unroll
            for (int r = 0; r < 4; ++r) {
                float v = acc[rf][nf][r] + bv;
                if (MODE == 2) v = fmaxf(v, 0.f);
                outp[(size_t)(rbase + r) * DIM + nf * 16 + c] = f2bf(v);
                if (MODE == 1) {
                    float m = (rbase + r < N_NODES) ? v : 0.f;
                    s_[nf] += m;
                    q_[nf] += m * m;
                }
            }
        }
    }

    if (MODE == 1) {
#pragma unroll
        for (int nf = 0; nf < 8; ++nf) {
            s_[nf] += __shfl_xor(s_[nf], 16);
            s_[nf] += __shfl_xor(s_[nf], 32);
            q_[nf] += __shfl_xor(q_[nf], 16);
            q_[nf] += __shfl_xor(q_[nf], 32);
        }
        if (lane < 16) {
#pragma unroll
            for (int nf = 0; nf < 8; ++nf) {
                ls[wid][nf * 16 + c] = s_[nf];
                lq[wid][nf * 16 + c] = q_[nf];
            }
        }
        __syncthreads();
        if (t < DIM) {
            atomicAdd(&bn_sum[t], ls[0][t] + ls[1][t] + ls[2][t] + ls[3][t]);
            atomicAdd(&bn_sumsq[t], lq[0][t] + lq[1][t] + lq[2][t] + lq[3][t]);
        }
    }
}

// ---------------------------------------------------------------------------
// Global add pool (bf16 in, f32 out); batch sorted
// ---------------------------------------------------------------------------
__global__ __launch_bounds__(256) void pool_bf(const u16* __restrict__ h,
                                               const int* __restrict__ batch,
                                               float* __restrict__ out) {
    int wv = (blockIdx.x * 256 + threadIdx.x) >> 6;
    int lane = threadIdx.x & 63;
    int base = wv * 32;
    if (base >= N_NODES) return;
    int end = base + 32;
    if (end > N_NODES) end = N_NODES;
    const uint32* h32 = (const uint32*)h;
    float ax = 0.f, ay = 0.f;
    int curg = batch[base];
    for (int n = base; n < end; ++n) {
        int g = batch[n];
        if (g != curg) {
            atomicAdd(&out[curg * DIM + lane * 2], ax);
            atomicAdd(&out[curg * DIM + lane * 2 + 1], ay);
            ax = 0.f;
            ay = 0.f;
            curg = g;
        }
        uint32 v = h32[(size_t)n * 64 + lane];
        ax += lo_bf(v);
        ay += hi_bf(v);
    }
    atomicAdd(&out[curg * DIM + lane * 2], ax);
    atomicAdd(&out[curg * DIM + lane * 2 + 1], ay);
}

// ---------------------------------------------------------------------------
extern "C" void kernel_launch(void* const* d_in, const int* in_sizes, int n_in,
                              void* d_out, int out_size, void* d_ws, size_t ws_size,
                              hipStream_t stream) {
    const float* x     = (const float*)d_in[0];
    const int*   ei    = (const int*)d_in[1];
    const int*   batch = (const int*)d_in[2];
    const float* Wn    = (const float*)d_in[3];
    const float* bnode = (const float*)d_in[4];
    const float* W1    = (const float*)d_in[5];
    const float* b1    = (const float*)d_in[6];
    const float* gamma = (const float*)d_in[7];
    const float* beta  = (const float*)d_in[8];
    const float* W2    = (const float*)d_in[9];
    const float* b2    = (const float*)d_in[10];
    float* out = (float*)d_out;

    const int* e_src = ei;
    const int* e_dst = ei + N_EDGES;

    // workspace layout
    const size_t MD = (size_t)M_PAD * DIM;
    u16* h   = (u16*)d_ws;
    u16* agg = h + MD;
    u16* y   = agg + MD;
    u16* WT  = y + MD;                      // 7 * 128 * 128 bf16, pre-swizzled
    int* row_ptr = (int*)(WT + 7 * DIM * DIM);
    int* col_src = row_ptr + N_NODES + 1;
    int* gcur    = col_src + N_EDGES;
    int* obase   = gcur + N_BUCKETS;
    float* bn_stats = (float*)(obase + N_BUCKETS);   // 3 layers * 2 * DIM
    // packed aliases y: used only during CSR build, before any GEMM writes y
    uint32* packed = (uint32*)y;            // 782*4864*4 B = 15.2 MB <= 25.6 MB

    const int GEMM_BLOCKS = M_PAD / 128;    // 782
    const int AGG_BLOCKS = (N_NODES * 64 + 255) / 256;   // 25000
    const int POOL_BLOCKS = (((N_NODES + 31) / 32) * 64 + 255) / 256;

    // ---- init + CSR build ----
    zero_misc<<<64, 256, 0, stream>>>(gcur, bn_stats, out,
                                      (uint32*)(agg + (size_t)N_NODES * DIM));
    bin_by_dst<<<BIN_BLOCKS, 256, 0, stream>>>(e_src, e_dst, gcur, packed);
    scan_buckets<<<1, 256, 0, stream>>>(gcur, obase, row_ptr);
    build_buckets<<<N_BUCKETS, 256, 0, stream>>>(packed, gcur, obase, row_ptr, col_src);

    // ---- weights (transposed + swizzled bf16) ----
    cvt_wt_all<<<7 * DIM, DIM, 0, stream>>>(Wn, W1, W2, WT);

    // ---- node encoder (fused f32->bf16) ----
    gemm_v2<0><<<GEMM_BLOCKS, 256, 0, stream>>>(x, WT, bnode, h, nullptr,
                                                nullptr, nullptr, nullptr);

    // ---- GIN layers ----
    for (int i = 0; i < N_LAYERS; ++i) {
        float* bn_sum = bn_stats + (size_t)i * 2 * DIM;
        float* bn_sumsq = bn_sum + DIM;
        aggregate_bf<<<AGG_BLOCKS, 256, 0, stream>>>(h, row_ptr, col_src, agg);
        gemm_v2<1><<<GEMM_BLOCKS, 256, 0, stream>>>(
            agg, WT + (size_t)(1 + i) * DIM * DIM, b1 + i * DIM, y, bn_sum,
            bn_sumsq, nullptr, nullptr);
        gemm_v2<2><<<GEMM_BLOCKS, 256, 0, stream>>>(
            y, WT + (size_t)(4 + i) * DIM * DIM, b2 + i * DIM, h, bn_sum,
            bn_sumsq, gamma + i * DIM, beta + i * DIM);
    }

    // ---- global add pool ----
    pool_bf<<<POOL_BLOCKS, 256, 0, stream>>>(h, batch, out);
}